// Round 7
// baseline (469.740 us; speedup 1.0000x reference)
//
#include <hip/hip_runtime.h>

#define NN 10000      // nodes
#define NE 320000     // edges (before self-loops)
#define NB 64         // graphs
#define CIN 128       // in_channels
#define CEC 64        // edge_channels
#define CHID 256      // hidden
#define CMLP 512
#define CNC 4
#define K1 (2 * CIN + CEC)    // 320
#define K23 (2 * CHID + CEC)  // 576

static __host__ int cdiv(int a, int b) { return (a + b - 1) / b; }

typedef short sfrag __attribute__((ext_vector_type(8)));   // 8 bf16 in 4 VGPRs
typedef float f4 __attribute__((ext_vector_type(4)));

static __device__ __forceinline__ ushort f2b(float f) {
  union { float f; unsigned u; } v; v.f = f;
  unsigned r = (v.u + 0x7fffu + ((v.u >> 16) & 1u)) >> 16;
  return (ushort)r;
}
static __device__ __forceinline__ float b2f(ushort u) {
  union { unsigned u; float f; } v; v.u = ((unsigned)u) << 16;
  return v.f;
}

// ---------------- setup kernels ----------------

__global__ __launch_bounds__(256) void k_init(int* __restrict__ ptr, float* __restrict__ pooled,
                                              float* __restrict__ counts, float* __restrict__ stats) {
  int i = blockIdx.x * 256 + threadIdx.x;
  if (i <= NN) ptr[i] = 0;
  if (i < NB * CHID) pooled[i] = 0.f;
  if (i < NB) counts[i] = 0.f;
  if (i < 6 * CHID) stats[i] = 0.f;
}

// blocks [0,1250): edge-degree histogram; blocks [1250,1290): batch histogram -> counts
__global__ __launch_bounds__(256) void k_count(const int* __restrict__ ei, int* __restrict__ ptr,
                                               const int* __restrict__ batch, float* __restrict__ counts) {
  int b = blockIdx.x;
  if (b < 1250) {
    int e = b * 256 + threadIdx.x;  // 1250*256 == NE exactly
    atomicAdd(&ptr[ei[NE + e] + 1], 1);
  } else {
    __shared__ int hist[NB];
    if (threadIdx.x < NB) hist[threadIdx.x] = 0;
    __syncthreads();
    int n = (b - 1250) * 256 + threadIdx.x;
    if (n < NN) atomicAdd(&hist[batch[n]], 1);
    __syncthreads();
    if (threadIdx.x < NB && hist[threadIdx.x]) atomicAdd(&counts[threadIdx.x], (float)hist[threadIdx.x]);
  }
}

// single-block inclusive scan over ptr[0..NN] + fused pos/degf writeout
__global__ __launch_bounds__(1024) void k_scan(int* __restrict__ ptr, int* __restrict__ pos,
                                               float* __restrict__ degf) {
  __shared__ int wsum[16];
  __shared__ int chtot;
  int carry = 0;
  const int n1 = NN + 1;
  const int lane = threadIdx.x & 63;
  const int wid = threadIdx.x >> 6;
  for (int base = 0; base < n1; base += 1024) {
    int i = base + threadIdx.x;
    int v = (i < n1) ? ptr[i] : 0;
    int sc = v;
#pragma unroll
    for (int d = 1; d < 64; d <<= 1) {
      int t = __shfl_up(sc, d);
      if (lane >= d) sc += t;
    }
    if (lane == 63) wsum[wid] = sc;
    __syncthreads();
    if (wid == 0 && lane < 16) {
      int ws = wsum[lane];
      int s2 = ws;
#pragma unroll
      for (int d = 1; d < 16; d <<= 1) {
        int t = __shfl_up(s2, d);
        if (lane >= d) s2 += t;
      }
      wsum[lane] = s2 - ws;  // exclusive
      if (lane == 15) chtot = s2;
    }
    __syncthreads();
    if (i < n1) ptr[i] = sc + wsum[wid] + carry;
    carry += chtot;
    __syncthreads();
  }
  for (int i = threadIdx.x; i < NN; i += 1024) {
    int p = ptr[i], q = ptr[i + 1];
    pos[i] = p;
    degf[i] = (float)(q - p + 1);  // +1 self-loop
  }
}

// counting-sort placement: srcs in CSR order + perm (original e -> sorted slot)
__global__ __launch_bounds__(256) void k_fill(const int* __restrict__ ei, int* __restrict__ pos,
                                              int* __restrict__ perm, int* __restrict__ srcs) {
  int e = blockIdx.x * 256 + threadIdx.x;  // 1250*256 == NE
  int d = ei[NE + e];
  int idx = atomicAdd(&pos[d], 1);
  perm[e] = idx;
  srcs[idx] = ei[e];
}

// permute edge_attr into CSR order, fp32 -> bf16. Streaming reads, scattered 128B writes.
__global__ __launch_bounds__(256) void k_perm(const float4* __restrict__ eattr, const int* __restrict__ perm,
                                              ushort* __restrict__ eattrs) {
  int tid = threadIdx.x;
  int e = blockIdx.x * 16 + (tid >> 4);  // 20000 blocks x 16 edges
  int c0 = (tid & 15) << 2;
  float4 v = eattr[(size_t)e * 16 + (c0 >> 2)];
  int sp = perm[e];
  ushort4 o = { f2b(v.x), f2b(v.y), f2b(v.z), f2b(v.w) };
  *(ushort4*)&eattrs[(size_t)sp * CEC + c0] = o;
}

// A1[:, 0:128] = bf16(degf * x); xb = bf16(x)
__global__ __launch_bounds__(256) void k_prep(const float4* __restrict__ x, const float* __restrict__ degf,
                                              ushort* __restrict__ A1, ushort* __restrict__ xb) {
  int gid = blockIdx.x * 256 + threadIdx.x;  // NN*32 = 320000 = 1250*256
  int node = gid >> 5;
  int c4 = (gid & 31) << 2;
  float d = degf[node];
  float4 v = x[gid];
  ushort4 o = { f2b(d * v.x), f2b(d * v.y), f2b(d * v.z), f2b(d * v.w) };
  *(ushort4*)&A1[(size_t)node * K1 + c4] = o;
  ushort4 xo = { f2b(v.x), f2b(v.y), f2b(v.z), f2b(v.w) };
  *(ushort4*)&xb[(size_t)node * CIN + c4] = xo;
}

// fused: ea_sum (streaming over CSR-ordered eattrs) + layer-1 x-gather (32-wide pipelined chunks)
__global__ __launch_bounds__(256) void k_eag(const ushort* __restrict__ eattrs, const ushort* __restrict__ xb,
                                             const int* __restrict__ ptr, const int* __restrict__ srcs,
                                             ushort* __restrict__ A1, ushort* __restrict__ A23) {
  int node = blockIdx.x * 4 + (threadIdx.x >> 6);
  int lane = threadIdx.x & 63;
  int s = ptr[node], e = ptr[node + 1];

  // edge-attr sum: contiguous bf16 rows, 4-row unrolled independent loads
  float ea_acc = 1.0f;  // PyG self-loop edge_attr fill
  for (int k = s; k < e; k += 4) {
    int r1 = min(k + 1, e - 1), r2 = min(k + 2, e - 1), r3 = min(k + 3, e - 1);
    float v0 = b2f(eattrs[(size_t)k * CEC + lane]);
    float t1 = b2f(eattrs[(size_t)r1 * CEC + lane]);
    float t2 = b2f(eattrs[(size_t)r2 * CEC + lane]);
    float t3 = b2f(eattrs[(size_t)r3 * CEC + lane]);
    ea_acc += v0;
    if (k + 1 < e) ea_acc += t1;
    if (k + 2 < e) ea_acc += t2;
    if (k + 3 < e) ea_acc += t3;
  }
  ushort eb = f2b(ea_acc);
  A1[(size_t)node * K1 + 2 * CIN + lane] = eb;
  A23[(size_t)node * K23 + 2 * CHID + lane] = eb;

  // layer-1 gather: 32 independent loads in flight, index prefetch pipelined
  ushort2 own = *(const ushort2*)&xb[(size_t)node * CIN + lane * 2];
  float gx = b2f(own.x), gy = b2f(own.y);
  int myi = (lane < 32 && s + lane < e) ? srcs[s + lane] : 0;
  for (int k0 = s; k0 < e; k0 += 32) {
    int rem = e - k0;
    int cur = myi;
    int nk = k0 + 32;
    if (nk < e) myi = (lane < 32 && nk + lane < e) ? srcs[nk + lane] : 0;
    if (rem >= 32) {
#pragma unroll
      for (int j = 0; j < 32; ++j) {
        int idx = __shfl(cur, j);
        ushort2 v = *(const ushort2*)&xb[(size_t)idx * CIN + lane * 2];
        gx += b2f(v.x); gy += b2f(v.y);
      }
    } else {
#pragma unroll
      for (int j = 0; j < 32; ++j) {
        int idx = __shfl(cur, j);
        ushort2 v = *(const ushort2*)&xb[(size_t)idx * CIN + lane * 2];
        if (j < rem) { gx += b2f(v.x); gy += b2f(v.y); }
      }
    }
  }
  ushort2 go = { f2b(gx), f2b(gy) };
  *(ushort2*)&A1[(size_t)node * K1 + CIN + lane * 2] = go;
}

// layers 2/3 gather: both 128-ch slices in one launch; 32-wide pipelined chunks
__global__ __launch_bounds__(256) void k_gather256(const ushort* __restrict__ hb, const int* __restrict__ ptr,
                                                   const int* __restrict__ srcs, ushort* __restrict__ A23) {
  int bx = blockIdx.x;
  int half = bx >= (NN / 4);
  int node = (bx - half * (NN / 4)) * 4 + (threadIdx.x >> 6);
  int coff = half << 7;
  int lane = threadIdx.x & 63;
  const ushort* hbl = hb + coff + lane * 2;
  ushort2 own = *(const ushort2*)&hbl[(size_t)node * CHID];
  float ax = b2f(own.x), ay = b2f(own.y);
  int s = ptr[node], e = ptr[node + 1];
  int myi = (lane < 32 && s + lane < e) ? srcs[s + lane] : 0;
  for (int k0 = s; k0 < e; k0 += 32) {
    int rem = e - k0;
    int cur = myi;
    int nk = k0 + 32;
    if (nk < e) myi = (lane < 32 && nk + lane < e) ? srcs[nk + lane] : 0;
    if (rem >= 32) {
#pragma unroll
      for (int j = 0; j < 32; ++j) {
        int idx = __shfl(cur, j);
        ushort2 v = *(const ushort2*)&hbl[(size_t)idx * CHID];
        ax += b2f(v.x); ay += b2f(v.y);
      }
    } else {
#pragma unroll
      for (int j = 0; j < 32; ++j) {
        int idx = __shfl(cur, j);
        ushort2 v = *(const ushort2*)&hbl[(size_t)idx * CHID];
        if (j < rem) { ax += b2f(v.x); ay += b2f(v.y); }
      }
    }
  }
  ushort2 o = { f2b(ax), f2b(ay) };
  *(ushort2*)&A23[(size_t)node * K23 + CHID + coff + lane * 2] = o;
}

// all three weight transposes in one launch: flat over 256*(K1+2*K23) = 376832 = 1472*256
__global__ __launch_bounds__(256) void k_wt3(const float* __restrict__ W1, const float* __restrict__ W2,
                                             const float* __restrict__ W3, ushort* __restrict__ Wt1,
                                             ushort* __restrict__ Wt2, ushort* __restrict__ Wt3) {
  int i = blockIdx.x * 256 + threadIdx.x;
  const float* W; ushort* Wt; int Ktot; int j = i;
  if (j < 256 * K1) { W = W1; Wt = Wt1; Ktot = K1; }
  else {
    j -= 256 * K1;
    if (j < 256 * K23) { W = W2; Wt = Wt2; Ktot = K23; }
    else { j -= 256 * K23; W = W3; Wt = Wt3; Ktot = K23; }
  }
  int n = j / Ktot;
  int k = j - n * Ktot;
  Wt[j] = f2b(W[(size_t)k * CHID + n]);
}

// ---------------- MFMA GEMM 64x64 tile, register-prefetch dbuf + fused bias/relu/BN-stats ----------------
__global__ __launch_bounds__(256) void k_gemm(const ushort* __restrict__ Ag, const ushort* __restrict__ Wt,
                                              const float* __restrict__ bias, const float* __restrict__ degf,
                                              float* __restrict__ out, float* __restrict__ colsum,
                                              float* __restrict__ colsq, int Ktot) {
  __shared__ ushort As[64 * 40];  // 64 rows x 32 k, stride 40 (16B-aligned, 2-way alias free)
  __shared__ ushort Bs[64 * 40];
  const int bm = blockIdx.x * 64;
  const int bn = blockIdx.y * 64;
  const int tid = threadIdx.x;
  const int w = tid >> 6;
  const int lane = tid & 63;
  const int ln = lane & 15;
  const int quad = lane >> 4;

  f4 acc[4];
#pragma unroll
  for (int nf = 0; nf < 4; ++nf) acc[nf] = (f4){0.f, 0.f, 0.f, 0.f};

  const int rA = tid >> 2;         // 0..63
  const int kq = (tid & 3) << 3;   // 0,8,16,24
  const int rowAc = min(bm + rA, NN - 1);  // clamp; garbage rows never stored
  const ushort* ap = Ag + (size_t)rowAc * Ktot + kq;
  const ushort* bp = Wt + (size_t)(bn + rA) * Ktot + kq;

  const int iters = Ktot >> 5;
  uint4 av = *(const uint4*)ap;
  uint4 bv = *(const uint4*)bp;
  for (int it = 0; it < iters; ++it) {
    *(uint4*)&As[rA * 40 + kq] = av;
    *(uint4*)&Bs[rA * 40 + kq] = bv;
    __syncthreads();
    if (it + 1 < iters) {  // prefetch next K-tile while MFMAs run
      av = *(const uint4*)(ap + (it + 1) * 32);
      bv = *(const uint4*)(bp + (it + 1) * 32);
    }
    sfrag a = *(const sfrag*)&As[(w * 16 + ln) * 40 + quad * 8];
#pragma unroll
    for (int nf = 0; nf < 4; ++nf) {
      sfrag b = *(const sfrag*)&Bs[(nf * 16 + ln) * 40 + quad * 8];
      acc[nf] = __builtin_amdgcn_mfma_f32_16x16x32_bf16(a, b, acc[nf], 0, 0, 0);
    }
    __syncthreads();
  }

  float bcol[4];
#pragma unroll
  for (int nf = 0; nf < 4; ++nf) bcol[nf] = bias[bn + nf * 16 + ln];
  float ssum[4] = {0.f, 0.f, 0.f, 0.f}, sqq[4] = {0.f, 0.f, 0.f, 0.f};
  int rbase = bm + w * 16 + quad * 4;
#pragma unroll
  for (int r = 0; r < 4; ++r) {
    int row = rbase + r;
    bool valid = row < NN;
    float d = valid ? degf[row] : 0.f;
#pragma unroll
    for (int nf = 0; nf < 4; ++nf) {
      float v = fmaxf(acc[nf][r] + d * bcol[nf], 0.f);
      if (valid) {
        out[(size_t)row * CHID + bn + nf * 16 + ln] = v;
        ssum[nf] += v;
        sqq[nf] += v * v;
      }
    }
  }
#pragma unroll
  for (int nf = 0; nf < 4; ++nf) {
    float s = ssum[nf], q = sqq[nf];
    s += __shfl_xor(s, 16); s += __shfl_xor(s, 32);
    q += __shfl_xor(q, 16); q += __shfl_xor(q, 32);
    if (quad == 0) {
      atomicAdd(&colsum[bn + nf * 16 + ln], s);
      atomicAdd(&colsq[bn + nf * 16 + ln], q);
    }
  }
}

// ---------------- BN apply (layers 1,2): inline bnfin; writes hb + next A-panel only ----------------
__global__ __launch_bounds__(256) void k_bnapply(const float4* __restrict__ t, const float* __restrict__ colsum,
                                                 const float* __restrict__ colsq, const float* __restrict__ g,
                                                 const float* __restrict__ be, ushort* __restrict__ Apanel,
                                                 ushort* __restrict__ hb, const float* __restrict__ degf) {
  int gid = blockIdx.x * 256 + threadIdx.x;  // NN*64
  int node = gid >> 6;
  int c4 = (gid & 63) << 2;
  float sc[4], sh[4];
#pragma unroll
  for (int j = 0; j < 4; ++j) {
    int c = c4 + j;
    float mu = colsum[c] * (1.f / (float)NN);
    float var = colsq[c] * (1.f / (float)NN) - mu * mu;
    float inv = rsqrtf(var + 1e-5f);
    sc[j] = g[c] * inv;
    sh[j] = be[c] - mu * sc[j];
  }
  float4 v = t[gid];
  float o0 = fmaxf(fmaf(v.x, sc[0], sh[0]), 0.f);
  float o1 = fmaxf(fmaf(v.y, sc[1], sh[1]), 0.f);
  float o2 = fmaxf(fmaf(v.z, sc[2], sh[2]), 0.f);
  float o3 = fmaxf(fmaf(v.w, sc[3], sh[3]), 0.f);
  ushort4 ho = { f2b(o0), f2b(o1), f2b(o2), f2b(o3) };
  *(ushort4*)&hb[(size_t)node * CHID + c4] = ho;
  float d = degf[node];
  ushort4 ao = { f2b(d * o0), f2b(d * o1), f2b(d * o2), f2b(d * o3) };
  *(ushort4*)&Apanel[(size_t)node * K23 + c4] = ao;
}

// ---------------- layer-3 BN + relu + segment pool, fused ----------------
__global__ __launch_bounds__(256) void k_poolbn(const float* __restrict__ t, const float* __restrict__ colsum,
                                                const float* __restrict__ colsq, const float* __restrict__ g,
                                                const float* __restrict__ be, const int* __restrict__ batch,
                                                float* __restrict__ pooled) {
  __shared__ int bsh[64];
  int r0 = blockIdx.x * 64;
  int c = threadIdx.x;
  int rows = min(64, NN - r0);
  if (c < rows) bsh[c] = batch[r0 + c];
  __syncthreads();
  float mu = colsum[c] * (1.f / (float)NN);
  float var = colsq[c] * (1.f / (float)NN) - mu * mu;
  float inv = rsqrtf(var + 1e-5f);
  float sc = g[c] * inv;
  float sh = be[c] - mu * sc;
  float acc = 0.f;
  int cur = bsh[0];
  for (int r = 0; r < rows; ++r) {
    int gg = bsh[r];
    if (gg != cur) {
      atomicAdd(&pooled[cur * CHID + c], acc);
      acc = 0.f;
      cur = gg;
    }
    acc += fmaxf(fmaf(t[(size_t)(r0 + r) * CHID + c], sc, sh), 0.f);
  }
  atomicAdd(&pooled[cur * CHID + c], acc);
}

// ---------------- MLP head (split: fc1 over 256 blocks, fc2 tiny) ----------------
__global__ __launch_bounds__(128) void k_fc1(const float* __restrict__ pooled, const float* __restrict__ counts,
                                             const float* __restrict__ nb, const float* __restrict__ w1,
                                             const float* __restrict__ b1, float* __restrict__ z) {
  int g = blockIdx.x >> 2;
  int o = ((blockIdx.x & 3) << 7) + threadIdx.x;
  __shared__ float zin[CHID + 1 + CIN];  // 385
  for (int i = threadIdx.x; i < CHID + 1 + CIN; i += 128) {
    zin[i] = (i < CHID) ? pooled[g * CHID + i]
           : (i == CHID) ? counts[g] * 0.025f  // / MAX_SIZE(40)
           : nb[g * CIN + (i - CHID - 1)];
  }
  __syncthreads();
  float acc = b1[o];
  for (int k = 0; k < CHID + 1 + CIN; ++k) acc = fmaf(zin[k], w1[k * CMLP + o], acc);
  z[g * CMLP + o] = fmaxf(acc, 0.f);
}

__global__ __launch_bounds__(64) void k_fc2(const float* __restrict__ z, const float* __restrict__ w2,
                                            const float* __restrict__ b2, float* __restrict__ out) {
  int g = blockIdx.x;
  int l = threadIdx.x;
  float p0 = 0.f, p1 = 0.f, p2 = 0.f, p3 = 0.f;
  for (int k = l; k < CMLP; k += 64) {
    float zv = z[g * CMLP + k];
    p0 = fmaf(zv, w2[k * CNC + 0], p0);
    p1 = fmaf(zv, w2[k * CNC + 1], p1);
    p2 = fmaf(zv, w2[k * CNC + 2], p2);
    p3 = fmaf(zv, w2[k * CNC + 3], p3);
  }
#pragma unroll
  for (int d = 1; d < 64; d <<= 1) {
    p0 += __shfl_xor(p0, d); p1 += __shfl_xor(p1, d);
    p2 += __shfl_xor(p2, d); p3 += __shfl_xor(p3, d);
  }
  if (l == 0) {
    out[g * CNC + 0] = p0 + b2[0];
    out[g * CNC + 1] = p1 + b2[1];
    out[g * CNC + 2] = p2 + b2[2];
    out[g * CNC + 3] = p3 + b2[3];
  }
}

// ---------------- launch ----------------

extern "C" void kernel_launch(void* const* d_in, const int* in_sizes, int n_in,
                              void* d_out, int out_size, void* d_ws, size_t ws_size,
                              hipStream_t stream) {
  const float* x     = (const float*)d_in[0];
  const int*   ei    = (const int*)d_in[1];
  const float* eattr = (const float*)d_in[2];
  const int*   batch = (const int*)d_in[3];
  const float* nbr   = (const float*)d_in[4];
  const float* W1 = (const float*)d_in[5];
  const float* b1 = (const float*)d_in[6];
  const float* g1 = (const float*)d_in[7];
  const float* be1 = (const float*)d_in[8];
  const float* W2 = (const float*)d_in[9];
  const float* b2 = (const float*)d_in[10];
  const float* g2 = (const float*)d_in[11];
  const float* be2 = (const float*)d_in[12];
  const float* W3 = (const float*)d_in[13];
  const float* b3 = (const float*)d_in[14];
  const float* g3 = (const float*)d_in[15];
  const float* be3 = (const float*)d_in[16];
  const float* fc1w = (const float*)d_in[17];
  const float* fc1b = (const float*)d_in[18];
  const float* fc2w = (const float*)d_in[19];
  const float* fc2b = (const float*)d_in[20];
  float* out = (float*)d_out;

  char* ws = (char*)d_ws;
  size_t off = 0;
  auto alloc = [&](size_t bytes) {
    void* p = ws + off;
    off = (off + bytes + 255) & ~(size_t)255;
    return p;
  };
  int*    ptr    = (int*)alloc((NN + 1) * sizeof(int));
  int*    pos    = (int*)alloc(NN * sizeof(int));
  float*  degf   = (float*)alloc(NN * sizeof(float));
  int*    perm   = (int*)alloc(NE * sizeof(int));
  int*    srcs   = (int*)alloc(NE * sizeof(int));
  ushort* eattrs = (ushort*)alloc((size_t)NE * CEC * sizeof(ushort));  // 41 MB CSR-ordered bf16
  ushort* A1     = (ushort*)alloc((size_t)NN * K1 * sizeof(ushort));
  ushort* A23    = (ushort*)alloc((size_t)NN * K23 * sizeof(ushort));
  ushort* Wt1    = (ushort*)alloc((size_t)256 * K1 * sizeof(ushort));
  ushort* Wt2    = (ushort*)alloc((size_t)256 * K23 * sizeof(ushort));
  ushort* Wt3    = (ushort*)alloc((size_t)256 * K23 * sizeof(ushort));
  ushort* xb     = (ushort*)alloc((size_t)NN * CIN * sizeof(ushort));
  ushort* hb     = (ushort*)alloc((size_t)NN * CHID * sizeof(ushort));
  float*  tmp    = (float*)alloc((size_t)NN * CHID * sizeof(float));
  float*  stats  = (float*)alloc(6 * CHID * sizeof(float));  // [layer][sum|sq][256]
  float*  pooled = (float*)alloc((size_t)NB * CHID * sizeof(float));
  float*  counts = (float*)alloc(NB * sizeof(float));
  float*  zmlp   = (float*)alloc((size_t)NB * CMLP * sizeof(float));
  (void)ws_size; (void)n_in; (void)in_sizes; (void)out_size;

  float* cs1 = stats + 0 * 512, *cq1 = stats + 0 * 512 + 256;
  float* cs2 = stats + 1 * 512, *cq2 = stats + 1 * 512 + 256;
  float* cs3 = stats + 2 * 512, *cq3 = stats + 2 * 512 + 256;

  // CSR + static aggregates
  k_init<<<cdiv(NN + 1, 256), 256, 0, stream>>>(ptr, pooled, counts, stats);
  k_count<<<1250 + 40, 256, 0, stream>>>(ei, ptr, batch, counts);
  k_scan<<<1, 1024, 0, stream>>>(ptr, pos, degf);
  k_fill<<<1250, 256, 0, stream>>>(ei, pos, perm, srcs);
  k_perm<<<NE / 16, 256, 0, stream>>>((const float4*)eattr, perm, eattrs);
  k_prep<<<1250, 256, 0, stream>>>((const float4*)x, degf, A1, xb);
  k_eag<<<NN / 4, 256, 0, stream>>>(eattrs, xb, ptr, srcs, A1, A23);
  k_wt3<<<1472, 256, 0, stream>>>(W1, W2, W3, Wt1, Wt2, Wt3);

  dim3 ggrid(cdiv(NN, 64), CHID / 64);

  // layer 1
  k_gemm<<<ggrid, 256, 0, stream>>>(A1, Wt1, b1, degf, tmp, cs1, cq1, K1);
  k_bnapply<<<cdiv(NN * 64, 256), 256, 0, stream>>>((const float4*)tmp, cs1, cq1, g1, be1, A23, hb, degf);

  // layer 2
  k_gather256<<<NN / 2, 256, 0, stream>>>(hb, ptr, srcs, A23);
  k_gemm<<<ggrid, 256, 0, stream>>>(A23, Wt2, b2, degf, tmp, cs2, cq2, K23);
  k_bnapply<<<cdiv(NN * 64, 256), 256, 0, stream>>>((const float4*)tmp, cs2, cq2, g2, be2, A23, hb, degf);

  // layer 3
  k_gather256<<<NN / 2, 256, 0, stream>>>(hb, ptr, srcs, A23);
  k_gemm<<<ggrid, 256, 0, stream>>>(A23, Wt3, b3, degf, tmp, cs3, cq3, K23);
  k_poolbn<<<cdiv(NN, 64), 256, 0, stream>>>(tmp, cs3, cq3, g3, be3, batch, pooled);

  // MLP head
  k_fc1<<<NB * 4, 128, 0, stream>>>(pooled, counts, nbr, fc1w, fc1b, zmlp);
  k_fc2<<<NB, 64, 0, stream>>>(zmlp, fc2w, fc2b, out);
}

// Round 8
// 423.382 us; speedup vs baseline: 1.1095x; 1.1095x over previous
//
#include <hip/hip_runtime.h>

#define NN 10000      // nodes
#define NE 320000     // edges (before self-loops)
#define NB 64         // graphs
#define CIN 128       // in_channels
#define CEC 64        // edge_channels
#define CHID 256      // hidden
#define CMLP 512
#define CNC 4
#define K1 (2 * CIN + CEC)    // 320
#define K23 (2 * CHID + CEC)  // 576

static __host__ int cdiv(int a, int b) { return (a + b - 1) / b; }

typedef short sfrag __attribute__((ext_vector_type(8)));   // 8 bf16 in 4 VGPRs
typedef float f4 __attribute__((ext_vector_type(4)));

static __device__ __forceinline__ ushort f2b(float f) {
  union { float f; unsigned u; } v; v.f = f;
  unsigned r = (v.u + 0x7fffu + ((v.u >> 16) & 1u)) >> 16;
  return (ushort)r;
}
static __device__ __forceinline__ float b2f(ushort u) {
  union { unsigned u; float f; } v; v.u = ((unsigned)u) << 16;
  return v.f;
}

// ---------------- setup kernels ----------------

__global__ __launch_bounds__(256) void k_init(int* __restrict__ ptr, float* __restrict__ pooled,
                                              float* __restrict__ counts, float* __restrict__ stats) {
  int i = blockIdx.x * 256 + threadIdx.x;
  if (i <= NN) ptr[i] = 0;
  if (i < NB * CHID) pooled[i] = 0.f;
  if (i < NB) counts[i] = 0.f;
  if (i < 6 * CHID) stats[i] = 0.f;
}

// blocks [0,1250): edge-degree histogram; blocks [1250,1290): batch histogram -> counts
__global__ __launch_bounds__(256) void k_count(const int* __restrict__ ei, int* __restrict__ ptr,
                                               const int* __restrict__ batch, float* __restrict__ counts) {
  int b = blockIdx.x;
  if (b < 1250) {
    int e = b * 256 + threadIdx.x;  // 1250*256 == NE exactly
    atomicAdd(&ptr[ei[NE + e] + 1], 1);
  } else {
    __shared__ int hist[NB];
    if (threadIdx.x < NB) hist[threadIdx.x] = 0;
    __syncthreads();
    int n = (b - 1250) * 256 + threadIdx.x;
    if (n < NN) atomicAdd(&hist[batch[n]], 1);
    __syncthreads();
    if (threadIdx.x < NB && hist[threadIdx.x]) atomicAdd(&counts[threadIdx.x], (float)hist[threadIdx.x]);
  }
}

// single-block inclusive scan over ptr[0..NN] + fused pos/degf writeout
__global__ __launch_bounds__(1024) void k_scan(int* __restrict__ ptr, int* __restrict__ pos,
                                               float* __restrict__ degf) {
  __shared__ int wsum[16];
  __shared__ int chtot;
  int carry = 0;
  const int n1 = NN + 1;
  const int lane = threadIdx.x & 63;
  const int wid = threadIdx.x >> 6;
  for (int base = 0; base < n1; base += 1024) {
    int i = base + threadIdx.x;
    int v = (i < n1) ? ptr[i] : 0;
    int sc = v;
#pragma unroll
    for (int d = 1; d < 64; d <<= 1) {
      int t = __shfl_up(sc, d);
      if (lane >= d) sc += t;
    }
    if (lane == 63) wsum[wid] = sc;
    __syncthreads();
    if (wid == 0 && lane < 16) {
      int ws = wsum[lane];
      int s2 = ws;
#pragma unroll
      for (int d = 1; d < 16; d <<= 1) {
        int t = __shfl_up(s2, d);
        if (lane >= d) s2 += t;
      }
      wsum[lane] = s2 - ws;  // exclusive
      if (lane == 15) chtot = s2;
    }
    __syncthreads();
    if (i < n1) ptr[i] = sc + wsum[wid] + carry;
    carry += chtot;
    __syncthreads();
  }
  for (int i = threadIdx.x; i < NN; i += 1024) {
    int p = ptr[i], q = ptr[i + 1];
    pos[i] = p;
    degf[i] = (float)(q - p + 1);  // +1 self-loop
  }
}

// counting-sort placement: srcs in CSR order + perm (original e -> sorted slot)
__global__ __launch_bounds__(256) void k_fill(const int* __restrict__ ei, int* __restrict__ pos,
                                              int* __restrict__ perm, int* __restrict__ srcs) {
  int e = blockIdx.x * 256 + threadIdx.x;  // 1250*256 == NE
  int d = ei[NE + e];
  int idx = atomicAdd(&pos[d], 1);
  perm[e] = idx;
  srcs[idx] = ei[e];
}

// merged: blocks [0,20000) permute edge_attr into CSR order (fp32->bf16);
//         blocks [20000,21250) build A1[:,0:128]=bf16(degf*x) and xb=bf16(x)
__global__ __launch_bounds__(256) void k_permprep(const float4* __restrict__ eattr, const int* __restrict__ perm,
                                                  ushort* __restrict__ eattrs, const float4* __restrict__ x,
                                                  const float* __restrict__ degf, ushort* __restrict__ A1,
                                                  ushort* __restrict__ xb) {
  int b = blockIdx.x;
  int tid = threadIdx.x;
  if (b < 20000) {
    int e = b * 16 + (tid >> 4);
    int c0 = (tid & 15) << 2;
    float4 v = eattr[(size_t)e * 16 + (c0 >> 2)];
    int sp = perm[e];
    ushort4 o = { f2b(v.x), f2b(v.y), f2b(v.z), f2b(v.w) };
    *(ushort4*)&eattrs[(size_t)sp * CEC + c0] = o;
  } else {
    int gid = (b - 20000) * 256 + tid;  // NN*32 = 320000
    int node = gid >> 5;
    int c4 = (gid & 31) << 2;
    float d = degf[node];
    float4 v = x[gid];
    ushort4 o = { f2b(d * v.x), f2b(d * v.y), f2b(d * v.z), f2b(d * v.w) };
    *(ushort4*)&A1[(size_t)node * K1 + c4] = o;
    ushort4 xo = { f2b(v.x), f2b(v.y), f2b(v.z), f2b(v.w) };
    *(ushort4*)&xb[(size_t)node * CIN + c4] = xo;
  }
}

// fused: ea_sum (streaming over CSR-ordered eattrs) + layer-1 x-gather
// 32-wide pipelined chunks; tail uses wave-uniform break so NO loads issue for j>=rem
__global__ __launch_bounds__(256) void k_eag(const ushort* __restrict__ eattrs, const ushort* __restrict__ xb,
                                             const int* __restrict__ ptr, const int* __restrict__ srcs,
                                             ushort* __restrict__ A1, ushort* __restrict__ A23) {
  int node = blockIdx.x * 4 + (threadIdx.x >> 6);
  int lane = threadIdx.x & 63;
  int s = ptr[node], e = ptr[node + 1];

  // edge-attr sum: contiguous bf16 rows, 4-row unrolled independent loads
  float ea_acc = 1.0f;  // PyG self-loop edge_attr fill
  for (int k = s; k < e; k += 4) {
    int r1 = min(k + 1, e - 1), r2 = min(k + 2, e - 1), r3 = min(k + 3, e - 1);
    float v0 = b2f(eattrs[(size_t)k * CEC + lane]);
    float t1 = b2f(eattrs[(size_t)r1 * CEC + lane]);
    float t2 = b2f(eattrs[(size_t)r2 * CEC + lane]);
    float t3 = b2f(eattrs[(size_t)r3 * CEC + lane]);
    ea_acc += v0;
    if (k + 1 < e) ea_acc += t1;
    if (k + 2 < e) ea_acc += t2;
    if (k + 3 < e) ea_acc += t3;
  }
  ushort eb = f2b(ea_acc);
  A1[(size_t)node * K1 + 2 * CIN + lane] = eb;
  A23[(size_t)node * K23 + 2 * CHID + lane] = eb;

  // layer-1 gather
  ushort2 own = *(const ushort2*)&xb[(size_t)node * CIN + lane * 2];
  float gx = b2f(own.x), gy = b2f(own.y);
  int myi = (lane < 32 && s + lane < e) ? srcs[s + lane] : 0;
  for (int k0 = s; k0 < e; k0 += 32) {
    int rem = e - k0;
    int cur = myi;
    int nk = k0 + 32;
    if (nk < e) myi = (lane < 32 && nk + lane < e) ? srcs[nk + lane] : 0;
    if (rem >= 32) {
#pragma unroll
      for (int j = 0; j < 32; ++j) {
        int idx = __shfl(cur, j);
        ushort2 v = *(const ushort2*)&xb[(size_t)idx * CIN + lane * 2];
        gx += b2f(v.x); gy += b2f(v.y);
      }
    } else {
#pragma unroll
      for (int j = 0; j < 32; ++j) {
        if (j >= rem) break;  // wave-uniform: no load issued past rem
        int idx = __shfl(cur, j);
        ushort2 v = *(const ushort2*)&xb[(size_t)idx * CIN + lane * 2];
        gx += b2f(v.x); gy += b2f(v.y);
      }
    }
  }
  ushort2 go = { f2b(gx), f2b(gy) };
  *(ushort2*)&A1[(size_t)node * K1 + CIN + lane * 2] = go;
}

// layers 2/3 gather: both 128-ch slices in one launch; 32-wide pipelined chunks, uniform-break tail
__global__ __launch_bounds__(256) void k_gather256(const ushort* __restrict__ hb, const int* __restrict__ ptr,
                                                   const int* __restrict__ srcs, ushort* __restrict__ A23) {
  int bx = blockIdx.x;
  int half = bx >= (NN / 4);
  int node = (bx - half * (NN / 4)) * 4 + (threadIdx.x >> 6);
  int coff = half << 7;
  int lane = threadIdx.x & 63;
  const ushort* hbl = hb + coff + lane * 2;
  ushort2 own = *(const ushort2*)&hbl[(size_t)node * CHID];
  float ax = b2f(own.x), ay = b2f(own.y);
  int s = ptr[node], e = ptr[node + 1];
  int myi = (lane < 32 && s + lane < e) ? srcs[s + lane] : 0;
  for (int k0 = s; k0 < e; k0 += 32) {
    int rem = e - k0;
    int cur = myi;
    int nk = k0 + 32;
    if (nk < e) myi = (lane < 32 && nk + lane < e) ? srcs[nk + lane] : 0;
    if (rem >= 32) {
#pragma unroll
      for (int j = 0; j < 32; ++j) {
        int idx = __shfl(cur, j);
        ushort2 v = *(const ushort2*)&hbl[(size_t)idx * CHID];
        ax += b2f(v.x); ay += b2f(v.y);
      }
    } else {
#pragma unroll
      for (int j = 0; j < 32; ++j) {
        if (j >= rem) break;  // wave-uniform: no load issued past rem
        int idx = __shfl(cur, j);
        ushort2 v = *(const ushort2*)&hbl[(size_t)idx * CHID];
        ax += b2f(v.x); ay += b2f(v.y);
      }
    }
  }
  ushort2 o = { f2b(ax), f2b(ay) };
  *(ushort2*)&A23[(size_t)node * K23 + CHID + coff + lane * 2] = o;
}

// all three weight transposes in one launch: flat over 256*(K1+2*K23) = 376832 = 1472*256
__global__ __launch_bounds__(256) void k_wt3(const float* __restrict__ W1, const float* __restrict__ W2,
                                             const float* __restrict__ W3, ushort* __restrict__ Wt1,
                                             ushort* __restrict__ Wt2, ushort* __restrict__ Wt3) {
  int i = blockIdx.x * 256 + threadIdx.x;
  const float* W; ushort* Wt; int Ktot; int j = i;
  if (j < 256 * K1) { W = W1; Wt = Wt1; Ktot = K1; }
  else {
    j -= 256 * K1;
    if (j < 256 * K23) { W = W2; Wt = Wt2; Ktot = K23; }
    else { j -= 256 * K23; W = W3; Wt = Wt3; Ktot = K23; }
  }
  int n = j / Ktot;
  int k = j - n * Ktot;
  Wt[j] = f2b(W[(size_t)k * CHID + n]);
}

// ---------------- MFMA GEMM (r5-proven 128x64 tile) + fused bias/relu/BN-stats ----------------
__global__ __launch_bounds__(256) void k_gemm(const ushort* __restrict__ Ag, const ushort* __restrict__ Wt,
                                              const float* __restrict__ bias, const float* __restrict__ degf,
                                              float* __restrict__ out, float* __restrict__ colsum,
                                              float* __restrict__ colsq, int Ktot) {
  __shared__ ushort As[128 * 40];  // 128 rows x 32 k, stride 40
  __shared__ ushort Bs[64 * 40];   // 64 n x 32 k
  const int bm = blockIdx.x * 128;
  const int bn = blockIdx.y * 64;
  const int tid = threadIdx.x;
  const int w = tid >> 6;
  const int lane = tid & 63;
  const int ln = lane & 15;
  const int quad = lane >> 4;

  f4 acc[2][4];
#pragma unroll
  for (int mf = 0; mf < 2; ++mf)
#pragma unroll
    for (int nf = 0; nf < 4; ++nf) acc[mf][nf] = (f4){0.f, 0.f, 0.f, 0.f};

  const int rA = tid >> 1;
  const int hk = (tid & 1) << 4;  // 0 or 16
  const int rowA = bm + rA;
  const int nB = tid >> 2;
  const int kq = (tid & 3) << 3;  // 0,8,16,24

  for (int k0 = 0; k0 < Ktot; k0 += 32) {
    uint4 v0 = {0, 0, 0, 0}, v1 = {0, 0, 0, 0};
    if (rowA < NN) {
      const uint4* p = (const uint4*)(Ag + (size_t)rowA * Ktot + k0 + hk);
      v0 = p[0]; v1 = p[1];
    }
    *(uint4*)&As[rA * 40 + hk] = v0;
    *(uint4*)&As[rA * 40 + hk + 8] = v1;
    uint4 bv = *(const uint4*)(Wt + (size_t)(bn + nB) * Ktot + k0 + kq);
    *(uint4*)&Bs[nB * 40 + kq] = bv;
    __syncthreads();

    sfrag a0 = *(const sfrag*)&As[(w * 32 + ln) * 40 + quad * 8];
    sfrag a1 = *(const sfrag*)&As[(w * 32 + 16 + ln) * 40 + quad * 8];
#pragma unroll
    for (int nf = 0; nf < 4; ++nf) {
      sfrag b = *(const sfrag*)&Bs[(nf * 16 + ln) * 40 + quad * 8];
      acc[0][nf] = __builtin_amdgcn_mfma_f32_16x16x32_bf16(a0, b, acc[0][nf], 0, 0, 0);
      acc[1][nf] = __builtin_amdgcn_mfma_f32_16x16x32_bf16(a1, b, acc[1][nf], 0, 0, 0);
    }
    __syncthreads();
  }

  float bcol[4];
#pragma unroll
  for (int nf = 0; nf < 4; ++nf) bcol[nf] = bias[bn + nf * 16 + ln];
  float ssum[4] = {0.f, 0.f, 0.f, 0.f}, sqq[4] = {0.f, 0.f, 0.f, 0.f};
#pragma unroll
  for (int mf = 0; mf < 2; ++mf) {
    int rbase = bm + w * 32 + mf * 16 + quad * 4;
#pragma unroll
    for (int r = 0; r < 4; ++r) {
      int row = rbase + r;
      bool valid = row < NN;
      float d = valid ? degf[row] : 0.f;
#pragma unroll
      for (int nf = 0; nf < 4; ++nf) {
        float v = fmaxf(acc[mf][nf][r] + d * bcol[nf], 0.f);
        if (valid) {
          out[(size_t)row * CHID + bn + nf * 16 + ln] = v;
          ssum[nf] += v;
          sqq[nf] += v * v;
        }
      }
    }
  }
#pragma unroll
  for (int nf = 0; nf < 4; ++nf) {
    float s = ssum[nf], q = sqq[nf];
    s += __shfl_xor(s, 16); s += __shfl_xor(s, 32);
    q += __shfl_xor(q, 16); q += __shfl_xor(q, 32);
    if (quad == 0) {
      atomicAdd(&colsum[bn + nf * 16 + ln], s);
      atomicAdd(&colsq[bn + nf * 16 + ln], q);
    }
  }
}

// ---------------- BN apply (layers 1,2): inline bnfin; writes hb + next A-panel only ----------------
__global__ __launch_bounds__(256) void k_bnapply(const float4* __restrict__ t, const float* __restrict__ colsum,
                                                 const float* __restrict__ colsq, const float* __restrict__ g,
                                                 const float* __restrict__ be, ushort* __restrict__ Apanel,
                                                 ushort* __restrict__ hb, const float* __restrict__ degf) {
  int gid = blockIdx.x * 256 + threadIdx.x;  // NN*64
  int node = gid >> 6;
  int c4 = (gid & 63) << 2;
  float sc[4], sh[4];
#pragma unroll
  for (int j = 0; j < 4; ++j) {
    int c = c4 + j;
    float mu = colsum[c] * (1.f / (float)NN);
    float var = colsq[c] * (1.f / (float)NN) - mu * mu;
    float inv = rsqrtf(var + 1e-5f);
    sc[j] = g[c] * inv;
    sh[j] = be[c] - mu * sc[j];
  }
  float4 v = t[gid];
  float o0 = fmaxf(fmaf(v.x, sc[0], sh[0]), 0.f);
  float o1 = fmaxf(fmaf(v.y, sc[1], sh[1]), 0.f);
  float o2 = fmaxf(fmaf(v.z, sc[2], sh[2]), 0.f);
  float o3 = fmaxf(fmaf(v.w, sc[3], sh[3]), 0.f);
  ushort4 ho = { f2b(o0), f2b(o1), f2b(o2), f2b(o3) };
  *(ushort4*)&hb[(size_t)node * CHID + c4] = ho;
  float d = degf[node];
  ushort4 ao = { f2b(d * o0), f2b(d * o1), f2b(d * o2), f2b(d * o3) };
  *(ushort4*)&Apanel[(size_t)node * K23 + c4] = ao;
}

// ---------------- layer-3 BN + relu + segment pool, fused ----------------
__global__ __launch_bounds__(256) void k_poolbn(const float* __restrict__ t, const float* __restrict__ colsum,
                                                const float* __restrict__ colsq, const float* __restrict__ g,
                                                const float* __restrict__ be, const int* __restrict__ batch,
                                                float* __restrict__ pooled) {
  __shared__ int bsh[64];
  int r0 = blockIdx.x * 64;
  int c = threadIdx.x;
  int rows = min(64, NN - r0);
  if (c < rows) bsh[c] = batch[r0 + c];
  __syncthreads();
  float mu = colsum[c] * (1.f / (float)NN);
  float var = colsq[c] * (1.f / (float)NN) - mu * mu;
  float inv = rsqrtf(var + 1e-5f);
  float sc = g[c] * inv;
  float sh = be[c] - mu * sc;
  float acc = 0.f;
  int cur = bsh[0];
  for (int r = 0; r < rows; ++r) {
    int gg = bsh[r];
    if (gg != cur) {
      atomicAdd(&pooled[cur * CHID + c], acc);
      acc = 0.f;
      cur = gg;
    }
    acc += fmaxf(fmaf(t[(size_t)(r0 + r) * CHID + c], sc, sh), 0.f);
  }
  atomicAdd(&pooled[cur * CHID + c], acc);
}

// ---------------- MLP head (split: fc1 over 256 blocks, fc2 tiny) ----------------
__global__ __launch_bounds__(128) void k_fc1(const float* __restrict__ pooled, const float* __restrict__ counts,
                                             const float* __restrict__ nb, const float* __restrict__ w1,
                                             const float* __restrict__ b1, float* __restrict__ z) {
  int g = blockIdx.x >> 2;
  int o = ((blockIdx.x & 3) << 7) + threadIdx.x;
  __shared__ float zin[CHID + 1 + CIN];  // 385
  for (int i = threadIdx.x; i < CHID + 1 + CIN; i += 128) {
    zin[i] = (i < CHID) ? pooled[g * CHID + i]
           : (i == CHID) ? counts[g] * 0.025f  // / MAX_SIZE(40)
           : nb[g * CIN + (i - CHID - 1)];
  }
  __syncthreads();
  float acc = b1[o];
  for (int k = 0; k < CHID + 1 + CIN; ++k) acc = fmaf(zin[k], w1[k * CMLP + o], acc);
  z[g * CMLP + o] = fmaxf(acc, 0.f);
}

__global__ __launch_bounds__(64) void k_fc2(const float* __restrict__ z, const float* __restrict__ w2,
                                            const float* __restrict__ b2, float* __restrict__ out) {
  int g = blockIdx.x;
  int l = threadIdx.x;
  float p0 = 0.f, p1 = 0.f, p2 = 0.f, p3 = 0.f;
  for (int k = l; k < CMLP; k += 64) {
    float zv = z[g * CMLP + k];
    p0 = fmaf(zv, w2[k * CNC + 0], p0);
    p1 = fmaf(zv, w2[k * CNC + 1], p1);
    p2 = fmaf(zv, w2[k * CNC + 2], p2);
    p3 = fmaf(zv, w2[k * CNC + 3], p3);
  }
#pragma unroll
  for (int d = 1; d < 64; d <<= 1) {
    p0 += __shfl_xor(p0, d); p1 += __shfl_xor(p1, d);
    p2 += __shfl_xor(p2, d); p3 += __shfl_xor(p3, d);
  }
  if (l == 0) {
    out[g * CNC + 0] = p0 + b2[0];
    out[g * CNC + 1] = p1 + b2[1];
    out[g * CNC + 2] = p2 + b2[2];
    out[g * CNC + 3] = p3 + b2[3];
  }
}

// ---------------- launch ----------------

extern "C" void kernel_launch(void* const* d_in, const int* in_sizes, int n_in,
                              void* d_out, int out_size, void* d_ws, size_t ws_size,
                              hipStream_t stream) {
  const float* x     = (const float*)d_in[0];
  const int*   ei    = (const int*)d_in[1];
  const float* eattr = (const float*)d_in[2];
  const int*   batch = (const int*)d_in[3];
  const float* nbr   = (const float*)d_in[4];
  const float* W1 = (const float*)d_in[5];
  const float* b1 = (const float*)d_in[6];
  const float* g1 = (const float*)d_in[7];
  const float* be1 = (const float*)d_in[8];
  const float* W2 = (const float*)d_in[9];
  const float* b2 = (const float*)d_in[10];
  const float* g2 = (const float*)d_in[11];
  const float* be2 = (const float*)d_in[12];
  const float* W3 = (const float*)d_in[13];
  const float* b3 = (const float*)d_in[14];
  const float* g3 = (const float*)d_in[15];
  const float* be3 = (const float*)d_in[16];
  const float* fc1w = (const float*)d_in[17];
  const float* fc1b = (const float*)d_in[18];
  const float* fc2w = (const float*)d_in[19];
  const float* fc2b = (const float*)d_in[20];
  float* out = (float*)d_out;

  char* ws = (char*)d_ws;
  size_t off = 0;
  auto alloc = [&](size_t bytes) {
    void* p = ws + off;
    off = (off + bytes + 255) & ~(size_t)255;
    return p;
  };
  int*    ptr    = (int*)alloc((NN + 1) * sizeof(int));
  int*    pos    = (int*)alloc(NN * sizeof(int));
  float*  degf   = (float*)alloc(NN * sizeof(float));
  int*    perm   = (int*)alloc(NE * sizeof(int));
  int*    srcs   = (int*)alloc(NE * sizeof(int));
  ushort* eattrs = (ushort*)alloc((size_t)NE * CEC * sizeof(ushort));  // 41 MB CSR-ordered bf16
  ushort* A1     = (ushort*)alloc((size_t)NN * K1 * sizeof(ushort));
  ushort* A23    = (ushort*)alloc((size_t)NN * K23 * sizeof(ushort));
  ushort* Wt1    = (ushort*)alloc((size_t)256 * K1 * sizeof(ushort));
  ushort* Wt2    = (ushort*)alloc((size_t)256 * K23 * sizeof(ushort));
  ushort* Wt3    = (ushort*)alloc((size_t)256 * K23 * sizeof(ushort));
  ushort* xb     = (ushort*)alloc((size_t)NN * CIN * sizeof(ushort));
  ushort* hb     = (ushort*)alloc((size_t)NN * CHID * sizeof(ushort));
  float*  tmp    = (float*)alloc((size_t)NN * CHID * sizeof(float));
  float*  stats  = (float*)alloc(6 * CHID * sizeof(float));  // [layer][sum|sq][256]
  float*  pooled = (float*)alloc((size_t)NB * CHID * sizeof(float));
  float*  counts = (float*)alloc(NB * sizeof(float));
  float*  zmlp   = (float*)alloc((size_t)NB * CMLP * sizeof(float));
  (void)ws_size; (void)n_in; (void)in_sizes; (void)out_size;

  float* cs1 = stats + 0 * 512, *cq1 = stats + 0 * 512 + 256;
  float* cs2 = stats + 1 * 512, *cq2 = stats + 1 * 512 + 256;
  float* cs3 = stats + 2 * 512, *cq3 = stats + 2 * 512 + 256;

  // CSR + static aggregates
  k_init<<<cdiv(NN + 1, 256), 256, 0, stream>>>(ptr, pooled, counts, stats);
  k_count<<<1250 + 40, 256, 0, stream>>>(ei, ptr, batch, counts);
  k_scan<<<1, 1024, 0, stream>>>(ptr, pos, degf);
  k_fill<<<1250, 256, 0, stream>>>(ei, pos, perm, srcs);
  k_permprep<<<20000 + 1250, 256, 0, stream>>>((const float4*)eattr, perm, eattrs,
                                               (const float4*)x, degf, A1, xb);
  k_eag<<<NN / 4, 256, 0, stream>>>(eattrs, xb, ptr, srcs, A1, A23);
  k_wt3<<<1472, 256, 0, stream>>>(W1, W2, W3, Wt1, Wt2, Wt3);

  dim3 ggrid(cdiv(NN, 128), CHID / 64);

  // layer 1
  k_gemm<<<ggrid, 256, 0, stream>>>(A1, Wt1, b1, degf, tmp, cs1, cq1, K1);
  k_bnapply<<<cdiv(NN * 64, 256), 256, 0, stream>>>((const float4*)tmp, cs1, cq1, g1, be1, A23, hb, degf);

  // layer 2
  k_gather256<<<NN / 2, 256, 0, stream>>>(hb, ptr, srcs, A23);
  k_gemm<<<ggrid, 256, 0, stream>>>(A23, Wt2, b2, degf, tmp, cs2, cq2, K23);
  k_bnapply<<<cdiv(NN * 64, 256), 256, 0, stream>>>((const float4*)tmp, cs2, cq2, g2, be2, A23, hb, degf);

  // layer 3
  k_gather256<<<NN / 2, 256, 0, stream>>>(hb, ptr, srcs, A23);
  k_gemm<<<ggrid, 256, 0, stream>>>(A23, Wt3, b3, degf, tmp, cs3, cq3, K23);
  k_poolbn<<<cdiv(NN, 64), 256, 0, stream>>>(tmp, cs3, cq3, g3, be3, batch, pooled);

  // MLP head
  k_fc1<<<NB * 4, 128, 0, stream>>>(pooled, counts, nbr, fc1w, fc1b, zmlp);
  k_fc2<<<NB, 64, 0, stream>>>(zmlp, fc2w, fc2b, out);
}

// Round 9
// 410.561 us; speedup vs baseline: 1.1441x; 1.0312x over previous
//
#include <hip/hip_runtime.h>

#define NN 10000      // nodes
#define NE 320000     // edges (before self-loops)
#define NB 64         // graphs
#define CIN 128       // in_channels
#define CEC 64        // edge_channels
#define CHID 256      // hidden
#define CMLP 512
#define CNC 4
#define K1 (2 * CIN + CEC)    // 320
#define K23 (2 * CHID + CEC)  // 576

static __host__ int cdiv(int a, int b) { return (a + b - 1) / b; }

typedef short sfrag __attribute__((ext_vector_type(8)));   // 8 bf16 in 4 VGPRs
typedef float f4 __attribute__((ext_vector_type(4)));

static __device__ __forceinline__ ushort f2b(float f) {
  union { float f; unsigned u; } v; v.f = f;
  unsigned r = (v.u + 0x7fffu + ((v.u >> 16) & 1u)) >> 16;
  return (ushort)r;
}
static __device__ __forceinline__ float b2f(ushort u) {
  union { unsigned u; float f; } v; v.u = ((unsigned)u) << 16;
  return v.f;
}

// ---------------- setup kernels ----------------

__global__ __launch_bounds__(256) void k_init(int* __restrict__ ptr, float* __restrict__ pooled,
                                              float* __restrict__ counts, float* __restrict__ stats) {
  int i = blockIdx.x * 256 + threadIdx.x;
  if (i <= NN) ptr[i] = 0;
  if (i < NB * CHID) pooled[i] = 0.f;
  if (i < NB) counts[i] = 0.f;
  if (i < 6 * CHID) stats[i] = 0.f;
}

// blocks [0,1250): edge-degree histogram; blocks [1250,1290): batch histogram -> counts
__global__ __launch_bounds__(256) void k_count(const int* __restrict__ ei, int* __restrict__ ptr,
                                               const int* __restrict__ batch, float* __restrict__ counts) {
  int b = blockIdx.x;
  if (b < 1250) {
    int e = b * 256 + threadIdx.x;  // 1250*256 == NE exactly
    atomicAdd(&ptr[ei[NE + e] + 1], 1);
  } else {
    __shared__ int hist[NB];
    if (threadIdx.x < NB) hist[threadIdx.x] = 0;
    __syncthreads();
    int n = (b - 1250) * 256 + threadIdx.x;
    if (n < NN) atomicAdd(&hist[batch[n]], 1);
    __syncthreads();
    if (threadIdx.x < NB && hist[threadIdx.x]) atomicAdd(&counts[threadIdx.x], (float)hist[threadIdx.x]);
  }
}

// single-block inclusive scan over ptr[0..NN] + fused pos/degf writeout
__global__ __launch_bounds__(1024) void k_scan(int* __restrict__ ptr, int* __restrict__ pos,
                                               float* __restrict__ degf) {
  __shared__ int wsum[16];
  __shared__ int chtot;
  int carry = 0;
  const int n1 = NN + 1;
  const int lane = threadIdx.x & 63;
  const int wid = threadIdx.x >> 6;
  for (int base = 0; base < n1; base += 1024) {
    int i = base + threadIdx.x;
    int v = (i < n1) ? ptr[i] : 0;
    int sc = v;
#pragma unroll
    for (int d = 1; d < 64; d <<= 1) {
      int t = __shfl_up(sc, d);
      if (lane >= d) sc += t;
    }
    if (lane == 63) wsum[wid] = sc;
    __syncthreads();
    if (wid == 0 && lane < 16) {
      int ws = wsum[lane];
      int s2 = ws;
#pragma unroll
      for (int d = 1; d < 16; d <<= 1) {
        int t = __shfl_up(s2, d);
        if (lane >= d) s2 += t;
      }
      wsum[lane] = s2 - ws;  // exclusive
      if (lane == 15) chtot = s2;
    }
    __syncthreads();
    if (i < n1) ptr[i] = sc + wsum[wid] + carry;
    carry += chtot;
    __syncthreads();
  }
  for (int i = threadIdx.x; i < NN; i += 1024) {
    int p = ptr[i], q = ptr[i + 1];
    pos[i] = p;
    degf[i] = (float)(q - p + 1);  // +1 self-loop
  }
}

// counting-sort placement: srcs in CSR order + perm (original e -> sorted slot)
__global__ __launch_bounds__(256) void k_fill(const int* __restrict__ ei, int* __restrict__ pos,
                                              int* __restrict__ perm, int* __restrict__ srcs) {
  int e = blockIdx.x * 256 + threadIdx.x;  // 1250*256 == NE
  int d = ei[NE + e];
  int idx = atomicAdd(&pos[d], 1);
  perm[e] = idx;
  srcs[idx] = ei[e];
}

// merged: [0,20000) permute edge_attr CSR-order fp32->bf16;
//         [20000,21250) A1[:,0:128]=bf16(degf*x), xb=bf16(x);
//         [21250,22722) weight transposes Wt1/Wt2/Wt3
__global__ __launch_bounds__(256) void k_permprep(const float4* __restrict__ eattr, const int* __restrict__ perm,
                                                  ushort* __restrict__ eattrs, const float4* __restrict__ x,
                                                  const float* __restrict__ degf, ushort* __restrict__ A1,
                                                  ushort* __restrict__ xb, const float* __restrict__ W1,
                                                  const float* __restrict__ W2, const float* __restrict__ W3,
                                                  ushort* __restrict__ Wt1, ushort* __restrict__ Wt2,
                                                  ushort* __restrict__ Wt3) {
  int b = blockIdx.x;
  int tid = threadIdx.x;
  if (b < 20000) {
    int e = b * 16 + (tid >> 4);
    int c0 = (tid & 15) << 2;
    float4 v = eattr[(size_t)e * 16 + (c0 >> 2)];
    int sp = perm[e];
    ushort4 o = { f2b(v.x), f2b(v.y), f2b(v.z), f2b(v.w) };
    *(ushort4*)&eattrs[(size_t)sp * CEC + c0] = o;
  } else if (b < 21250) {
    int gid = (b - 20000) * 256 + tid;  // NN*32 = 320000
    int node = gid >> 5;
    int c4 = (gid & 31) << 2;
    float d = degf[node];
    float4 v = x[gid];
    ushort4 o = { f2b(d * v.x), f2b(d * v.y), f2b(d * v.z), f2b(d * v.w) };
    *(ushort4*)&A1[(size_t)node * K1 + c4] = o;
    ushort4 xo = { f2b(v.x), f2b(v.y), f2b(v.z), f2b(v.w) };
    *(ushort4*)&xb[(size_t)node * CIN + c4] = xo;
  } else {
    int j = (b - 21250) * 256 + tid;  // 256*(K1+2*K23) = 376832
    const float* W; ushort* Wt; int Ktot;
    if (j < 256 * K1) { W = W1; Wt = Wt1; Ktot = K1; }
    else {
      j -= 256 * K1;
      if (j < 256 * K23) { W = W2; Wt = Wt2; Ktot = K23; }
      else { j -= 256 * K23; W = W3; Wt = Wt3; Ktot = K23; }
    }
    int n = j / Ktot;
    int k = j - n * Ktot;
    Wt[j] = f2b(W[(size_t)k * CHID + n]);
  }
}

// fused: ea_sum (512B wave-loads over CSR-ordered eattrs: 4 rows/load) + layer-1 x-gather
__global__ __launch_bounds__(256) void k_eag(const ushort* __restrict__ eattrs, const ushort* __restrict__ xb,
                                             const int* __restrict__ ptr, const int* __restrict__ srcs,
                                             ushort* __restrict__ A1, ushort* __restrict__ A23) {
  int node = blockIdx.x * 4 + (threadIdx.x >> 6);
  int lane = threadIdx.x & 63;
  int s = ptr[node], e = ptr[node + 1];
  int nrows = e - s;
  const int lane16 = lane & 15;
  const int lgrp = lane >> 4;

  // ea-sum: lane l holds channels 4*(l&15)..+3 of row (4g + l>>4). One 512B wave-load per 4 rows.
  float4 av = {0.f, 0.f, 0.f, 0.f};
  const ushort* ebase = eattrs + (size_t)s * CEC;
  int full4 = nrows & ~3;
#pragma unroll 2
  for (int r0 = 0; r0 < full4; r0 += 4) {
    ushort4 v = *(const ushort4*)&ebase[(size_t)(r0 + lgrp) * CEC + lane16 * 4];
    av.x += b2f(v.x); av.y += b2f(v.y); av.z += b2f(v.z); av.w += b2f(v.w);
  }
  if (full4 + lgrp < nrows) {
    ushort4 v = *(const ushort4*)&ebase[(size_t)(full4 + lgrp) * CEC + lane16 * 4];
    av.x += b2f(v.x); av.y += b2f(v.y); av.z += b2f(v.z); av.w += b2f(v.w);
  }
  av.x += __shfl_xor(av.x, 16); av.x += __shfl_xor(av.x, 32);
  av.y += __shfl_xor(av.y, 16); av.y += __shfl_xor(av.y, 32);
  av.z += __shfl_xor(av.z, 16); av.z += __shfl_xor(av.z, 32);
  av.w += __shfl_xor(av.w, 16); av.w += __shfl_xor(av.w, 32);
  if (lane < 16) {  // +1.0 self-loop fill
    ushort4 eo = { f2b(av.x + 1.f), f2b(av.y + 1.f), f2b(av.z + 1.f), f2b(av.w + 1.f) };
    *(ushort4*)&A1[(size_t)node * K1 + 2 * CIN + lane16 * 4] = eo;
    *(ushort4*)&A23[(size_t)node * K23 + 2 * CHID + lane16 * 4] = eo;
  }

  // layer-1 gather: 32-wide pipelined chunks, uniform-break tail
  ushort2 own = *(const ushort2*)&xb[(size_t)node * CIN + lane * 2];
  float gx = b2f(own.x), gy = b2f(own.y);
  int myi = (lane < 32 && s + lane < e) ? srcs[s + lane] : 0;
  for (int k0 = s; k0 < e; k0 += 32) {
    int rem = e - k0;
    int cur = myi;
    int nk = k0 + 32;
    if (nk < e) myi = (lane < 32 && nk + lane < e) ? srcs[nk + lane] : 0;
    if (rem >= 32) {
#pragma unroll
      for (int j = 0; j < 32; ++j) {
        int idx = __shfl(cur, j);
        ushort2 v = *(const ushort2*)&xb[(size_t)idx * CIN + lane * 2];
        gx += b2f(v.x); gy += b2f(v.y);
      }
    } else {
#pragma unroll
      for (int j = 0; j < 32; ++j) {
        if (j >= rem) break;  // wave-uniform: no load issued past rem
        int idx = __shfl(cur, j);
        ushort2 v = *(const ushort2*)&xb[(size_t)idx * CIN + lane * 2];
        gx += b2f(v.x); gy += b2f(v.y);
      }
    }
  }
  ushort2 go = { f2b(gx), f2b(gy) };
  *(ushort2*)&A1[(size_t)node * K1 + CIN + lane * 2] = go;
}

// layers 2/3 gather: single pass, full 512B row per wave-load (ushort4/lane)
__global__ __launch_bounds__(256) void k_gather256(const ushort* __restrict__ hb, const int* __restrict__ ptr,
                                                   const int* __restrict__ srcs, ushort* __restrict__ A23) {
  int node = blockIdx.x * 4 + (threadIdx.x >> 6);
  int lane = threadIdx.x & 63;
  ushort4 own = *(const ushort4*)&hb[(size_t)node * CHID + lane * 4];
  float ax = b2f(own.x), ay = b2f(own.y), az = b2f(own.z), aw = b2f(own.w);
  int s = ptr[node], e = ptr[node + 1];
  int myi = (lane < 32 && s + lane < e) ? srcs[s + lane] : 0;
  for (int k0 = s; k0 < e; k0 += 32) {
    int rem = e - k0;
    int cur = myi;
    int nk = k0 + 32;
    if (nk < e) myi = (lane < 32 && nk + lane < e) ? srcs[nk + lane] : 0;
    if (rem >= 32) {
#pragma unroll
      for (int j = 0; j < 32; ++j) {
        int idx = __shfl(cur, j);
        ushort4 v = *(const ushort4*)&hb[(size_t)idx * CHID + lane * 4];
        ax += b2f(v.x); ay += b2f(v.y); az += b2f(v.z); aw += b2f(v.w);
      }
    } else {
#pragma unroll
      for (int j = 0; j < 32; ++j) {
        if (j >= rem) break;  // wave-uniform
        int idx = __shfl(cur, j);
        ushort4 v = *(const ushort4*)&hb[(size_t)idx * CHID + lane * 4];
        ax += b2f(v.x); ay += b2f(v.y); az += b2f(v.z); aw += b2f(v.w);
      }
    }
  }
  ushort4 o = { f2b(ax), f2b(ay), f2b(az), f2b(aw) };
  *(ushort4*)&A23[(size_t)node * K23 + CHID + lane * 4] = o;
}

// ---------------- MFMA GEMM (128x64 tile) + fused bias/relu/BN-stats; bf16 out ----------------
__global__ __launch_bounds__(256) void k_gemm(const ushort* __restrict__ Ag, const ushort* __restrict__ Wt,
                                              const float* __restrict__ bias, const float* __restrict__ degf,
                                              ushort* __restrict__ outb, float* __restrict__ colsum,
                                              float* __restrict__ colsq, int Ktot) {
  __shared__ ushort As[128 * 40];  // 128 rows x 32 k, stride 40
  __shared__ ushort Bs[64 * 40];   // 64 n x 32 k
  const int bm = blockIdx.x * 128;
  const int bn = blockIdx.y * 64;
  const int tid = threadIdx.x;
  const int w = tid >> 6;
  const int lane = tid & 63;
  const int ln = lane & 15;
  const int quad = lane >> 4;

  f4 acc[2][4];
#pragma unroll
  for (int mf = 0; mf < 2; ++mf)
#pragma unroll
    for (int nf = 0; nf < 4; ++nf) acc[mf][nf] = (f4){0.f, 0.f, 0.f, 0.f};

  const int rA = tid >> 1;
  const int hk = (tid & 1) << 4;  // 0 or 16
  const int rowA = bm + rA;
  const int nB = tid >> 2;
  const int kq = (tid & 3) << 3;  // 0,8,16,24

  for (int k0 = 0; k0 < Ktot; k0 += 32) {
    uint4 v0 = {0, 0, 0, 0}, v1 = {0, 0, 0, 0};
    if (rowA < NN) {
      const uint4* p = (const uint4*)(Ag + (size_t)rowA * Ktot + k0 + hk);
      v0 = p[0]; v1 = p[1];
    }
    *(uint4*)&As[rA * 40 + hk] = v0;
    *(uint4*)&As[rA * 40 + hk + 8] = v1;
    uint4 bv = *(const uint4*)(Wt + (size_t)(bn + nB) * Ktot + k0 + kq);
    *(uint4*)&Bs[nB * 40 + kq] = bv;
    __syncthreads();

    sfrag a0 = *(const sfrag*)&As[(w * 32 + ln) * 40 + quad * 8];
    sfrag a1 = *(const sfrag*)&As[(w * 32 + 16 + ln) * 40 + quad * 8];
#pragma unroll
    for (int nf = 0; nf < 4; ++nf) {
      sfrag b = *(const sfrag*)&Bs[(nf * 16 + ln) * 40 + quad * 8];
      acc[0][nf] = __builtin_amdgcn_mfma_f32_16x16x32_bf16(a0, b, acc[0][nf], 0, 0, 0);
      acc[1][nf] = __builtin_amdgcn_mfma_f32_16x16x32_bf16(a1, b, acc[1][nf], 0, 0, 0);
    }
    __syncthreads();
  }

  float bcol[4];
#pragma unroll
  for (int nf = 0; nf < 4; ++nf) bcol[nf] = bias[bn + nf * 16 + ln];
  float ssum[4] = {0.f, 0.f, 0.f, 0.f}, sqq[4] = {0.f, 0.f, 0.f, 0.f};
#pragma unroll
  for (int mf = 0; mf < 2; ++mf) {
    int rbase = bm + w * 32 + mf * 16 + quad * 4;
#pragma unroll
    for (int r = 0; r < 4; ++r) {
      int row = rbase + r;
      bool valid = row < NN;
      float d = valid ? degf[row] : 0.f;
#pragma unroll
      for (int nf = 0; nf < 4; ++nf) {
        float v = fmaxf(acc[mf][nf][r] + d * bcol[nf], 0.f);
        if (valid) {
          outb[(size_t)row * CHID + bn + nf * 16 + ln] = f2b(v);
          ssum[nf] += v;
          sqq[nf] += v * v;
        }
      }
    }
  }
#pragma unroll
  for (int nf = 0; nf < 4; ++nf) {
    float s = ssum[nf], q = sqq[nf];
    s += __shfl_xor(s, 16); s += __shfl_xor(s, 32);
    q += __shfl_xor(q, 16); q += __shfl_xor(q, 32);
    if (quad == 0) {
      atomicAdd(&colsum[bn + nf * 16 + ln], s);
      atomicAdd(&colsq[bn + nf * 16 + ln], q);
    }
  }
}

// ---------------- BN apply (layers 1,2): inline bnfin; bf16 in; writes hb + next A-panel ----------------
__global__ __launch_bounds__(256) void k_bnapply(const ushort* __restrict__ t, const float* __restrict__ colsum,
                                                 const float* __restrict__ colsq, const float* __restrict__ g,
                                                 const float* __restrict__ be, ushort* __restrict__ Apanel,
                                                 ushort* __restrict__ hb, const float* __restrict__ degf) {
  int gid = blockIdx.x * 256 + threadIdx.x;  // NN*64
  int node = gid >> 6;
  int c4 = (gid & 63) << 2;
  float sc[4], sh[4];
#pragma unroll
  for (int j = 0; j < 4; ++j) {
    int c = c4 + j;
    float mu = colsum[c] * (1.f / (float)NN);
    float var = colsq[c] * (1.f / (float)NN) - mu * mu;
    float inv = rsqrtf(var + 1e-5f);
    sc[j] = g[c] * inv;
    sh[j] = be[c] - mu * sc[j];
  }
  ushort4 tv = *(const ushort4*)&t[(size_t)node * CHID + c4];
  float o0 = fmaxf(fmaf(b2f(tv.x), sc[0], sh[0]), 0.f);
  float o1 = fmaxf(fmaf(b2f(tv.y), sc[1], sh[1]), 0.f);
  float o2 = fmaxf(fmaf(b2f(tv.z), sc[2], sh[2]), 0.f);
  float o3 = fmaxf(fmaf(b2f(tv.w), sc[3], sh[3]), 0.f);
  ushort4 ho = { f2b(o0), f2b(o1), f2b(o2), f2b(o3) };
  *(ushort4*)&hb[(size_t)node * CHID + c4] = ho;
  float d = degf[node];
  ushort4 ao = { f2b(d * o0), f2b(d * o1), f2b(d * o2), f2b(d * o3) };
  *(ushort4*)&Apanel[(size_t)node * K23 + c4] = ao;
}

// ---------------- layer-3 BN + relu + segment pool, fused (bf16 in) ----------------
__global__ __launch_bounds__(256) void k_poolbn(const ushort* __restrict__ t, const float* __restrict__ colsum,
                                                const float* __restrict__ colsq, const float* __restrict__ g,
                                                const float* __restrict__ be, const int* __restrict__ batch,
                                                float* __restrict__ pooled) {
  __shared__ int bsh[64];
  int r0 = blockIdx.x * 64;
  int c = threadIdx.x;
  int rows = min(64, NN - r0);
  if (c < rows) bsh[c] = batch[r0 + c];
  __syncthreads();
  float mu = colsum[c] * (1.f / (float)NN);
  float var = colsq[c] * (1.f / (float)NN) - mu * mu;
  float inv = rsqrtf(var + 1e-5f);
  float sc = g[c] * inv;
  float sh = be[c] - mu * sc;
  float acc = 0.f;
  int cur = bsh[0];
  for (int r = 0; r < rows; ++r) {
    int gg = bsh[r];
    if (gg != cur) {
      atomicAdd(&pooled[cur * CHID + c], acc);
      acc = 0.f;
      cur = gg;
    }
    acc += fmaxf(fmaf(b2f(t[(size_t)(r0 + r) * CHID + c]), sc, sh), 0.f);
  }
  atomicAdd(&pooled[cur * CHID + c], acc);
}

// ---------------- MLP head: one block per graph, 512 threads, shfl reduce ----------------
__global__ __launch_bounds__(512) void k_mlp(const float* __restrict__ pooled, const float* __restrict__ counts,
                                             const float* __restrict__ nb, const float* __restrict__ w1,
                                             const float* __restrict__ b1, const float* __restrict__ w2,
                                             const float* __restrict__ b2, float* __restrict__ out) {
  int g = blockIdx.x;
  int t = threadIdx.x;
  int wid = t >> 6, wl = t & 63;
  __shared__ float zin[CHID + 1 + CIN];  // 385
  __shared__ float red[8];
  if (t < CHID) zin[t] = pooled[g * CHID + t];
  else if (t == CHID) zin[CHID] = counts[g] * 0.025f;  // / MAX_SIZE(40)
  else if (t < CHID + 1 + CIN) zin[t] = nb[g * CIN + (t - CHID - 1)];
  __syncthreads();
  float acc = b1[t];
  for (int k = 0; k < CHID + 1 + CIN; ++k) acc = fmaf(zin[k], w1[k * CMLP + t], acc);
  float z = fmaxf(acc, 0.f);
#pragma unroll
  for (int n = 0; n < CNC; ++n) {
    float part = z * w2[t * CNC + n];
#pragma unroll
    for (int d = 1; d < 64; d <<= 1) part += __shfl_xor(part, d);
    if (wl == 0) red[wid] = part;
    __syncthreads();
    if (t == 0) {
      float tot = 0.f;
#pragma unroll
      for (int i = 0; i < 8; ++i) tot += red[i];
      out[g * CNC + n] = tot + b2[n];
    }
    __syncthreads();
  }
}

// ---------------- launch ----------------

extern "C" void kernel_launch(void* const* d_in, const int* in_sizes, int n_in,
                              void* d_out, int out_size, void* d_ws, size_t ws_size,
                              hipStream_t stream) {
  const float* x     = (const float*)d_in[0];
  const int*   ei    = (const int*)d_in[1];
  const float* eattr = (const float*)d_in[2];
  const int*   batch = (const int*)d_in[3];
  const float* nbr   = (const float*)d_in[4];
  const float* W1 = (const float*)d_in[5];
  const float* b1 = (const float*)d_in[6];
  const float* g1 = (const float*)d_in[7];
  const float* be1 = (const float*)d_in[8];
  const float* W2 = (const float*)d_in[9];
  const float* b2 = (const float*)d_in[10];
  const float* g2 = (const float*)d_in[11];
  const float* be2 = (const float*)d_in[12];
  const float* W3 = (const float*)d_in[13];
  const float* b3 = (const float*)d_in[14];
  const float* g3 = (const float*)d_in[15];
  const float* be3 = (const float*)d_in[16];
  const float* fc1w = (const float*)d_in[17];
  const float* fc1b = (const float*)d_in[18];
  const float* fc2w = (const float*)d_in[19];
  const float* fc2b = (const float*)d_in[20];
  float* out = (float*)d_out;

  char* ws = (char*)d_ws;
  size_t off = 0;
  auto alloc = [&](size_t bytes) {
    void* p = ws + off;
    off = (off + bytes + 255) & ~(size_t)255;
    return p;
  };
  int*    ptr    = (int*)alloc((NN + 1) * sizeof(int));
  int*    pos    = (int*)alloc(NN * sizeof(int));
  float*  degf   = (float*)alloc(NN * sizeof(float));
  int*    perm   = (int*)alloc(NE * sizeof(int));
  int*    srcs   = (int*)alloc(NE * sizeof(int));
  ushort* eattrs = (ushort*)alloc((size_t)NE * CEC * sizeof(ushort));  // 41 MB CSR-ordered bf16
  ushort* A1     = (ushort*)alloc((size_t)NN * K1 * sizeof(ushort));
  ushort* A23    = (ushort*)alloc((size_t)NN * K23 * sizeof(ushort));
  ushort* Wt1    = (ushort*)alloc((size_t)256 * K1 * sizeof(ushort));
  ushort* Wt2    = (ushort*)alloc((size_t)256 * K23 * sizeof(ushort));
  ushort* Wt3    = (ushort*)alloc((size_t)256 * K23 * sizeof(ushort));
  ushort* xb     = (ushort*)alloc((size_t)NN * CIN * sizeof(ushort));
  ushort* hb     = (ushort*)alloc((size_t)NN * CHID * sizeof(ushort));
  ushort* tmp    = (ushort*)alloc((size_t)NN * CHID * sizeof(ushort));  // bf16 pre-BN h
  float*  stats  = (float*)alloc(6 * CHID * sizeof(float));  // [layer][sum|sq][256]
  float*  pooled = (float*)alloc((size_t)NB * CHID * sizeof(float));
  float*  counts = (float*)alloc(NB * sizeof(float));
  (void)ws_size; (void)n_in; (void)in_sizes; (void)out_size;

  float* cs1 = stats + 0 * 512, *cq1 = stats + 0 * 512 + 256;
  float* cs2 = stats + 1 * 512, *cq2 = stats + 1 * 512 + 256;
  float* cs3 = stats + 2 * 512, *cq3 = stats + 2 * 512 + 256;

  // CSR + static aggregates
  k_init<<<cdiv(NN + 1, 256), 256, 0, stream>>>(ptr, pooled, counts, stats);
  k_count<<<1250 + 40, 256, 0, stream>>>(ei, ptr, batch, counts);
  k_scan<<<1, 1024, 0, stream>>>(ptr, pos, degf);
  k_fill<<<1250, 256, 0, stream>>>(ei, pos, perm, srcs);
  k_permprep<<<20000 + 1250 + 1472, 256, 0, stream>>>((const float4*)eattr, perm, eattrs,
                                                      (const float4*)x, degf, A1, xb,
                                                      W1, W2, W3, Wt1, Wt2, Wt3);
  k_eag<<<NN / 4, 256, 0, stream>>>(eattrs, xb, ptr, srcs, A1, A23);

  dim3 ggrid(cdiv(NN, 128), CHID / 64);

  // layer 1
  k_gemm<<<ggrid, 256, 0, stream>>>(A1, Wt1, b1, degf, tmp, cs1, cq1, K1);
  k_bnapply<<<cdiv(NN * 64, 256), 256, 0, stream>>>(tmp, cs1, cq1, g1, be1, A23, hb, degf);

  // layer 2
  k_gather256<<<NN / 4, 256, 0, stream>>>(hb, ptr, srcs, A23);
  k_gemm<<<ggrid, 256, 0, stream>>>(A23, Wt2, b2, degf, tmp, cs2, cq2, K23);
  k_bnapply<<<cdiv(NN * 64, 256), 256, 0, stream>>>(tmp, cs2, cq2, g2, be2, A23, hb, degf);

  // layer 3
  k_gather256<<<NN / 4, 256, 0, stream>>>(hb, ptr, srcs, A23);
  k_gemm<<<ggrid, 256, 0, stream>>>(A23, Wt3, b3, degf, tmp, cs3, cq3, K23);
  k_poolbn<<<cdiv(NN, 64), 256, 0, stream>>>(tmp, cs3, cq3, g3, be3, batch, pooled);

  // MLP head
  k_mlp<<<NB, 512, 0, stream>>>(pooled, counts, nbr, fc1w, fc1b, fc2w, fc2b, out);
}

// Round 10
// 409.271 us; speedup vs baseline: 1.1477x; 1.0032x over previous
//
#include <hip/hip_runtime.h>

#define NN 10000      // nodes
#define NE 320000     // edges (before self-loops)
#define NB 64         // graphs
#define CIN 128       // in_channels
#define CEC 64        // edge_channels
#define CHID 256      // hidden
#define CMLP 512
#define CNC 4
#define K1 (2 * CIN + CEC)    // 320
#define K23 (2 * CHID + CEC)  // 576

static __host__ int cdiv(int a, int b) { return (a + b - 1) / b; }

typedef short sfrag __attribute__((ext_vector_type(8)));   // 8 bf16 in 4 VGPRs
typedef float f4 __attribute__((ext_vector_type(4)));

static __device__ __forceinline__ ushort f2b(float f) {
  union { float f; unsigned u; } v; v.f = f;
  unsigned r = (v.u + 0x7fffu + ((v.u >> 16) & 1u)) >> 16;
  return (ushort)r;
}
static __device__ __forceinline__ float b2f(ushort u) {
  union { unsigned u; float f; } v; v.u = ((unsigned)u) << 16;
  return v.f;
}

// ---------------- setup kernels ----------------

__global__ __launch_bounds__(256) void k_init(int* __restrict__ ptr, float* __restrict__ pooled,
                                              float* __restrict__ counts, float* __restrict__ stats) {
  int i = blockIdx.x * 256 + threadIdx.x;
  if (i <= NN) ptr[i] = 0;
  if (i < NB * CHID) pooled[i] = 0.f;
  if (i < NB) counts[i] = 0.f;
  if (i < 6 * CHID) stats[i] = 0.f;
}

// blocks [0,1250): edge-degree histogram; blocks [1250,1290): batch histogram -> counts
__global__ __launch_bounds__(256) void k_count(const int* __restrict__ ei, int* __restrict__ ptr,
                                               const int* __restrict__ batch, float* __restrict__ counts) {
  int b = blockIdx.x;
  if (b < 1250) {
    int e = b * 256 + threadIdx.x;  // 1250*256 == NE exactly
    atomicAdd(&ptr[ei[NE + e] + 1], 1);
  } else {
    __shared__ int hist[NB];
    if (threadIdx.x < NB) hist[threadIdx.x] = 0;
    __syncthreads();
    int n = (b - 1250) * 256 + threadIdx.x;
    if (n < NN) atomicAdd(&hist[batch[n]], 1);
    __syncthreads();
    if (threadIdx.x < NB && hist[threadIdx.x]) atomicAdd(&counts[threadIdx.x], (float)hist[threadIdx.x]);
  }
}

// single-block inclusive scan over ptr[0..NN] + fused pos/degf writeout
__global__ __launch_bounds__(1024) void k_scan(int* __restrict__ ptr, int* __restrict__ pos,
                                               float* __restrict__ degf) {
  __shared__ int wsum[16];
  __shared__ int chtot;
  int carry = 0;
  const int n1 = NN + 1;
  const int lane = threadIdx.x & 63;
  const int wid = threadIdx.x >> 6;
  for (int base = 0; base < n1; base += 1024) {
    int i = base + threadIdx.x;
    int v = (i < n1) ? ptr[i] : 0;
    int sc = v;
#pragma unroll
    for (int d = 1; d < 64; d <<= 1) {
      int t = __shfl_up(sc, d);
      if (lane >= d) sc += t;
    }
    if (lane == 63) wsum[wid] = sc;
    __syncthreads();
    if (wid == 0 && lane < 16) {
      int ws = wsum[lane];
      int s2 = ws;
#pragma unroll
      for (int d = 1; d < 16; d <<= 1) {
        int t = __shfl_up(s2, d);
        if (lane >= d) s2 += t;
      }
      wsum[lane] = s2 - ws;  // exclusive
      if (lane == 15) chtot = s2;
    }
    __syncthreads();
    if (i < n1) ptr[i] = sc + wsum[wid] + carry;
    carry += chtot;
    __syncthreads();
  }
  for (int i = threadIdx.x; i < NN; i += 1024) {
    int p = ptr[i], q = ptr[i + 1];
    pos[i] = p;
    degf[i] = (float)(q - p + 1);  // +1 self-loop
  }
}

// counting-sort placement: srcs in CSR order + perm (original e -> sorted slot)
__global__ __launch_bounds__(256) void k_fill(const int* __restrict__ ei, int* __restrict__ pos,
                                              int* __restrict__ perm, int* __restrict__ srcs) {
  int e = blockIdx.x * 256 + threadIdx.x;  // 1250*256 == NE
  int d = ei[NE + e];
  int idx = atomicAdd(&pos[d], 1);
  perm[e] = idx;
  srcs[idx] = ei[e];
}

// merged: [0,20000) permute edge_attr CSR-order fp32->bf16;
//         [20000,21250) A1[:,0:128]=bf16(degf*x), xb=bf16(x);
//         [21250,22722) weight transposes Wt1/Wt2/Wt3
__global__ __launch_bounds__(256) void k_permprep(const float4* __restrict__ eattr, const int* __restrict__ perm,
                                                  ushort* __restrict__ eattrs, const float4* __restrict__ x,
                                                  const float* __restrict__ degf, ushort* __restrict__ A1,
                                                  ushort* __restrict__ xb, const float* __restrict__ W1,
                                                  const float* __restrict__ W2, const float* __restrict__ W3,
                                                  ushort* __restrict__ Wt1, ushort* __restrict__ Wt2,
                                                  ushort* __restrict__ Wt3) {
  int b = blockIdx.x;
  int tid = threadIdx.x;
  if (b < 20000) {
    int e = b * 16 + (tid >> 4);
    int c0 = (tid & 15) << 2;
    float4 v = eattr[(size_t)e * 16 + (c0 >> 2)];
    int sp = perm[e];
    ushort4 o = { f2b(v.x), f2b(v.y), f2b(v.z), f2b(v.w) };
    *(ushort4*)&eattrs[(size_t)sp * CEC + c0] = o;
  } else if (b < 21250) {
    int gid = (b - 20000) * 256 + tid;  // NN*32 = 320000
    int node = gid >> 5;
    int c4 = (gid & 31) << 2;
    float d = degf[node];
    float4 v = x[gid];
    ushort4 o = { f2b(d * v.x), f2b(d * v.y), f2b(d * v.z), f2b(d * v.w) };
    *(ushort4*)&A1[(size_t)node * K1 + c4] = o;
    ushort4 xo = { f2b(v.x), f2b(v.y), f2b(v.z), f2b(v.w) };
    *(ushort4*)&xb[(size_t)node * CIN + c4] = xo;
  } else {
    int j = (b - 21250) * 256 + tid;  // 256*(K1+2*K23) = 376832
    const float* W; ushort* Wt; int Ktot;
    if (j < 256 * K1) { W = W1; Wt = Wt1; Ktot = K1; }
    else {
      j -= 256 * K1;
      if (j < 256 * K23) { W = W2; Wt = Wt2; Ktot = K23; }
      else { j -= 256 * K23; W = W3; Wt = Wt3; Ktot = K23; }
    }
    int n = j / Ktot;
    int k = j - n * Ktot;
    Wt[j] = f2b(W[(size_t)k * CHID + n]);
  }
}

// fused: ea_sum (512B wave-loads over CSR-ordered eattrs: 4 rows/load) + layer-1 x-gather
__global__ __launch_bounds__(256) void k_eag(const ushort* __restrict__ eattrs, const ushort* __restrict__ xb,
                                             const int* __restrict__ ptr, const int* __restrict__ srcs,
                                             ushort* __restrict__ A1, ushort* __restrict__ A23) {
  int node = blockIdx.x * 4 + (threadIdx.x >> 6);
  int lane = threadIdx.x & 63;
  int s = ptr[node], e = ptr[node + 1];
  int nrows = e - s;
  const int lane16 = lane & 15;
  const int lgrp = lane >> 4;

  // ea-sum: lane l holds channels 4*(l&15)..+3 of row (4g + l>>4). One 512B wave-load per 4 rows.
  float4 av = {0.f, 0.f, 0.f, 0.f};
  const ushort* ebase = eattrs + (size_t)s * CEC;
  int full4 = nrows & ~3;
#pragma unroll 2
  for (int r0 = 0; r0 < full4; r0 += 4) {
    ushort4 v = *(const ushort4*)&ebase[(size_t)(r0 + lgrp) * CEC + lane16 * 4];
    av.x += b2f(v.x); av.y += b2f(v.y); av.z += b2f(v.z); av.w += b2f(v.w);
  }
  if (full4 + lgrp < nrows) {
    ushort4 v = *(const ushort4*)&ebase[(size_t)(full4 + lgrp) * CEC + lane16 * 4];
    av.x += b2f(v.x); av.y += b2f(v.y); av.z += b2f(v.z); av.w += b2f(v.w);
  }
  av.x += __shfl_xor(av.x, 16); av.x += __shfl_xor(av.x, 32);
  av.y += __shfl_xor(av.y, 16); av.y += __shfl_xor(av.y, 32);
  av.z += __shfl_xor(av.z, 16); av.z += __shfl_xor(av.z, 32);
  av.w += __shfl_xor(av.w, 16); av.w += __shfl_xor(av.w, 32);
  if (lane < 16) {  // +1.0 self-loop fill
    ushort4 eo = { f2b(av.x + 1.f), f2b(av.y + 1.f), f2b(av.z + 1.f), f2b(av.w + 1.f) };
    *(ushort4*)&A1[(size_t)node * K1 + 2 * CIN + lane16 * 4] = eo;
    *(ushort4*)&A23[(size_t)node * K23 + 2 * CHID + lane16 * 4] = eo;
  }

  // layer-1 gather: 32-wide pipelined chunks, uniform-break tail
  ushort2 own = *(const ushort2*)&xb[(size_t)node * CIN + lane * 2];
  float gx = b2f(own.x), gy = b2f(own.y);
  int myi = (lane < 32 && s + lane < e) ? srcs[s + lane] : 0;
  for (int k0 = s; k0 < e; k0 += 32) {
    int rem = e - k0;
    int cur = myi;
    int nk = k0 + 32;
    if (nk < e) myi = (lane < 32 && nk + lane < e) ? srcs[nk + lane] : 0;
    if (rem >= 32) {
#pragma unroll
      for (int j = 0; j < 32; ++j) {
        int idx = __shfl(cur, j);
        ushort2 v = *(const ushort2*)&xb[(size_t)idx * CIN + lane * 2];
        gx += b2f(v.x); gy += b2f(v.y);
      }
    } else {
#pragma unroll
      for (int j = 0; j < 32; ++j) {
        if (j >= rem) break;  // wave-uniform: no load issued past rem
        int idx = __shfl(cur, j);
        ushort2 v = *(const ushort2*)&xb[(size_t)idx * CIN + lane * 2];
        gx += b2f(v.x); gy += b2f(v.y);
      }
    }
  }
  ushort2 go = { f2b(gx), f2b(gy) };
  *(ushort2*)&A1[(size_t)node * K1 + CIN + lane * 2] = go;
}

// layers 2/3: fused BN-apply + gather. Wave per node, h = relu(bn(tmp)) computed inline.
// Writes A23 dh-panel (degf*h_node) and G-panel (h_node + sum h_src).
__global__ __launch_bounds__(256) void k_gbn(const ushort* __restrict__ tmp, const float* __restrict__ colsum,
                                             const float* __restrict__ colsq, const float* __restrict__ g,
                                             const float* __restrict__ be, const int* __restrict__ ptr,
                                             const int* __restrict__ srcs, const float* __restrict__ degf,
                                             ushort* __restrict__ A23) {
  int node = blockIdx.x * 4 + (threadIdx.x >> 6);
  int lane = threadIdx.x & 63;
  int c4 = lane << 2;
  // per-lane BN constants for channels c4..c4+3
  float sc[4], sh[4];
#pragma unroll
  for (int j = 0; j < 4; ++j) {
    int c = c4 + j;
    float mu = colsum[c] * (1.f / (float)NN);
    float var = colsq[c] * (1.f / (float)NN) - mu * mu;
    float inv = rsqrtf(var + 1e-5f);
    sc[j] = g[c] * inv;
    sh[j] = be[c] - mu * sc[j];
  }
  // own row
  ushort4 tv = *(const ushort4*)&tmp[(size_t)node * CHID + c4];
  float o0 = fmaxf(fmaf(b2f(tv.x), sc[0], sh[0]), 0.f);
  float o1 = fmaxf(fmaf(b2f(tv.y), sc[1], sh[1]), 0.f);
  float o2 = fmaxf(fmaf(b2f(tv.z), sc[2], sh[2]), 0.f);
  float o3 = fmaxf(fmaf(b2f(tv.w), sc[3], sh[3]), 0.f);
  float d = degf[node];
  ushort4 ao = { f2b(d * o0), f2b(d * o1), f2b(d * o2), f2b(d * o3) };
  *(ushort4*)&A23[(size_t)node * K23 + c4] = ao;

  // gather: G = h_node + sum over neighbors of relu(bn(tmp[src]))
  float ax = o0, ay = o1, az = o2, aw = o3;
  int s = ptr[node], e = ptr[node + 1];
  int myi = (lane < 32 && s + lane < e) ? srcs[s + lane] : 0;
  for (int k0 = s; k0 < e; k0 += 32) {
    int rem = e - k0;
    int cur = myi;
    int nk = k0 + 32;
    if (nk < e) myi = (lane < 32 && nk + lane < e) ? srcs[nk + lane] : 0;
    if (rem >= 32) {
#pragma unroll
      for (int j = 0; j < 32; ++j) {
        int idx = __shfl(cur, j);
        ushort4 v = *(const ushort4*)&tmp[(size_t)idx * CHID + c4];
        ax += fmaxf(fmaf(b2f(v.x), sc[0], sh[0]), 0.f);
        ay += fmaxf(fmaf(b2f(v.y), sc[1], sh[1]), 0.f);
        az += fmaxf(fmaf(b2f(v.z), sc[2], sh[2]), 0.f);
        aw += fmaxf(fmaf(b2f(v.w), sc[3], sh[3]), 0.f);
      }
    } else {
#pragma unroll
      for (int j = 0; j < 32; ++j) {
        if (j >= rem) break;  // wave-uniform: no load issued past rem
        int idx = __shfl(cur, j);
        ushort4 v = *(const ushort4*)&tmp[(size_t)idx * CHID + c4];
        ax += fmaxf(fmaf(b2f(v.x), sc[0], sh[0]), 0.f);
        ay += fmaxf(fmaf(b2f(v.y), sc[1], sh[1]), 0.f);
        az += fmaxf(fmaf(b2f(v.z), sc[2], sh[2]), 0.f);
        aw += fmaxf(fmaf(b2f(v.w), sc[3], sh[3]), 0.f);
      }
    }
  }
  ushort4 o = { f2b(ax), f2b(ay), f2b(az), f2b(aw) };
  *(ushort4*)&A23[(size_t)node * K23 + CHID + c4] = o;
}

// ---------------- MFMA GEMM (128x64 tile) + fused bias/relu/BN-stats; bf16 out ----------------
__global__ __launch_bounds__(256) void k_gemm(const ushort* __restrict__ Ag, const ushort* __restrict__ Wt,
                                              const float* __restrict__ bias, const float* __restrict__ degf,
                                              ushort* __restrict__ outb, float* __restrict__ colsum,
                                              float* __restrict__ colsq, int Ktot) {
  __shared__ ushort As[128 * 40];  // 128 rows x 32 k, stride 40
  __shared__ ushort Bs[64 * 40];   // 64 n x 32 k
  const int bm = blockIdx.x * 128;
  const int bn = blockIdx.y * 64;
  const int tid = threadIdx.x;
  const int w = tid >> 6;
  const int lane = tid & 63;
  const int ln = lane & 15;
  const int quad = lane >> 4;

  f4 acc[2][4];
#pragma unroll
  for (int mf = 0; mf < 2; ++mf)
#pragma unroll
    for (int nf = 0; nf < 4; ++nf) acc[mf][nf] = (f4){0.f, 0.f, 0.f, 0.f};

  const int rA = tid >> 1;
  const int hk = (tid & 1) << 4;  // 0 or 16
  const int rowA = bm + rA;
  const int nB = tid >> 2;
  const int kq = (tid & 3) << 3;  // 0,8,16,24

  for (int k0 = 0; k0 < Ktot; k0 += 32) {
    uint4 v0 = {0, 0, 0, 0}, v1 = {0, 0, 0, 0};
    if (rowA < NN) {
      const uint4* p = (const uint4*)(Ag + (size_t)rowA * Ktot + k0 + hk);
      v0 = p[0]; v1 = p[1];
    }
    *(uint4*)&As[rA * 40 + hk] = v0;
    *(uint4*)&As[rA * 40 + hk + 8] = v1;
    uint4 bv = *(const uint4*)(Wt + (size_t)(bn + nB) * Ktot + k0 + kq);
    *(uint4*)&Bs[nB * 40 + kq] = bv;
    __syncthreads();

    sfrag a0 = *(const sfrag*)&As[(w * 32 + ln) * 40 + quad * 8];
    sfrag a1 = *(const sfrag*)&As[(w * 32 + 16 + ln) * 40 + quad * 8];
#pragma unroll
    for (int nf = 0; nf < 4; ++nf) {
      sfrag b = *(const sfrag*)&Bs[(nf * 16 + ln) * 40 + quad * 8];
      acc[0][nf] = __builtin_amdgcn_mfma_f32_16x16x32_bf16(a0, b, acc[0][nf], 0, 0, 0);
      acc[1][nf] = __builtin_amdgcn_mfma_f32_16x16x32_bf16(a1, b, acc[1][nf], 0, 0, 0);
    }
    __syncthreads();
  }

  float bcol[4];
#pragma unroll
  for (int nf = 0; nf < 4; ++nf) bcol[nf] = bias[bn + nf * 16 + ln];
  float ssum[4] = {0.f, 0.f, 0.f, 0.f}, sqq[4] = {0.f, 0.f, 0.f, 0.f};
#pragma unroll
  for (int mf = 0; mf < 2; ++mf) {
    int rbase = bm + w * 32 + mf * 16 + quad * 4;
#pragma unroll
    for (int r = 0; r < 4; ++r) {
      int row = rbase + r;
      bool valid = row < NN;
      float d = valid ? degf[row] : 0.f;
#pragma unroll
      for (int nf = 0; nf < 4; ++nf) {
        float v = fmaxf(acc[mf][nf][r] + d * bcol[nf], 0.f);
        if (valid) {
          outb[(size_t)row * CHID + bn + nf * 16 + ln] = f2b(v);
          ssum[nf] += v;
          sqq[nf] += v * v;
        }
      }
    }
  }
#pragma unroll
  for (int nf = 0; nf < 4; ++nf) {
    float s = ssum[nf], q = sqq[nf];
    s += __shfl_xor(s, 16); s += __shfl_xor(s, 32);
    q += __shfl_xor(q, 16); q += __shfl_xor(q, 32);
    if (quad == 0) {
      atomicAdd(&colsum[bn + nf * 16 + ln], s);
      atomicAdd(&colsq[bn + nf * 16 + ln], q);
    }
  }
}

// ---------------- layer-3 BN + relu + segment pool, fused (bf16 in) ----------------
__global__ __launch_bounds__(256) void k_poolbn(const ushort* __restrict__ t, const float* __restrict__ colsum,
                                                const float* __restrict__ colsq, const float* __restrict__ g,
                                                const float* __restrict__ be, const int* __restrict__ batch,
                                                float* __restrict__ pooled) {
  __shared__ int bsh[64];
  int r0 = blockIdx.x * 64;
  int c = threadIdx.x;
  int rows = min(64, NN - r0);
  if (c < rows) bsh[c] = batch[r0 + c];
  __syncthreads();
  float mu = colsum[c] * (1.f / (float)NN);
  float var = colsq[c] * (1.f / (float)NN) - mu * mu;
  float inv = rsqrtf(var + 1e-5f);
  float sc = g[c] * inv;
  float sh = be[c] - mu * sc;
  float acc = 0.f;
  int cur = bsh[0];
  for (int r = 0; r < rows; ++r) {
    int gg = bsh[r];
    if (gg != cur) {
      atomicAdd(&pooled[cur * CHID + c], acc);
      acc = 0.f;
      cur = gg;
    }
    acc += fmaxf(fmaf(b2f(t[(size_t)(r0 + r) * CHID + c]), sc, sh), 0.f);
  }
  atomicAdd(&pooled[cur * CHID + c], acc);
}

// ---------------- MLP head: one block per graph, 512 threads, shfl reduce ----------------
__global__ __launch_bounds__(512) void k_mlp(const float* __restrict__ pooled, const float* __restrict__ counts,
                                             const float* __restrict__ nb, const float* __restrict__ w1,
                                             const float* __restrict__ b1, const float* __restrict__ w2,
                                             const float* __restrict__ b2, float* __restrict__ out) {
  int g = blockIdx.x;
  int t = threadIdx.x;
  int wid = t >> 6, wl = t & 63;
  __shared__ float zin[CHID + 1 + CIN];  // 385
  __shared__ float red[8];
  if (t < CHID) zin[t] = pooled[g * CHID + t];
  else if (t == CHID) zin[CHID] = counts[g] * 0.025f;  // / MAX_SIZE(40)
  else if (t < CHID + 1 + CIN) zin[t] = nb[g * CIN + (t - CHID - 1)];
  __syncthreads();
  float acc = b1[t];
  for (int k = 0; k < CHID + 1 + CIN; ++k) acc = fmaf(zin[k], w1[k * CMLP + t], acc);
  float z = fmaxf(acc, 0.f);
#pragma unroll
  for (int n = 0; n < CNC; ++n) {
    float part = z * w2[t * CNC + n];
#pragma unroll
    for (int d = 1; d < 64; d <<= 1) part += __shfl_xor(part, d);
    if (wl == 0) red[wid] = part;
    __syncthreads();
    if (t == 0) {
      float tot = 0.f;
#pragma unroll
      for (int i = 0; i < 8; ++i) tot += red[i];
      out[g * CNC + n] = tot + b2[n];
    }
    __syncthreads();
  }
}

// ---------------- launch ----------------

extern "C" void kernel_launch(void* const* d_in, const int* in_sizes, int n_in,
                              void* d_out, int out_size, void* d_ws, size_t ws_size,
                              hipStream_t stream) {
  const float* x     = (const float*)d_in[0];
  const int*   ei    = (const int*)d_in[1];
  const float* eattr = (const float*)d_in[2];
  const int*   batch = (const int*)d_in[3];
  const float* nbr   = (const float*)d_in[4];
  const float* W1 = (const float*)d_in[5];
  const float* b1 = (const float*)d_in[6];
  const float* g1 = (const float*)d_in[7];
  const float* be1 = (const float*)d_in[8];
  const float* W2 = (const float*)d_in[9];
  const float* b2 = (const float*)d_in[10];
  const float* g2 = (const float*)d_in[11];
  const float* be2 = (const float*)d_in[12];
  const float* W3 = (const float*)d_in[13];
  const float* b3 = (const float*)d_in[14];
  const float* g3 = (const float*)d_in[15];
  const float* be3 = (const float*)d_in[16];
  const float* fc1w = (const float*)d_in[17];
  const float* fc1b = (const float*)d_in[18];
  const float* fc2w = (const float*)d_in[19];
  const float* fc2b = (const float*)d_in[20];
  float* out = (float*)d_out;

  char* ws = (char*)d_ws;
  size_t off = 0;
  auto alloc = [&](size_t bytes) {
    void* p = ws + off;
    off = (off + bytes + 255) & ~(size_t)255;
    return p;
  };
  int*    ptr    = (int*)alloc((NN + 1) * sizeof(int));
  int*    pos    = (int*)alloc(NN * sizeof(int));
  float*  degf   = (float*)alloc(NN * sizeof(float));
  int*    perm   = (int*)alloc(NE * sizeof(int));
  int*    srcs   = (int*)alloc(NE * sizeof(int));
  ushort* eattrs = (ushort*)alloc((size_t)NE * CEC * sizeof(ushort));  // 41 MB CSR-ordered bf16
  ushort* A1     = (ushort*)alloc((size_t)NN * K1 * sizeof(ushort));
  ushort* A23    = (ushort*)alloc((size_t)NN * K23 * sizeof(ushort));
  ushort* Wt1    = (ushort*)alloc((size_t)256 * K1 * sizeof(ushort));
  ushort* Wt2    = (ushort*)alloc((size_t)256 * K23 * sizeof(ushort));
  ushort* Wt3    = (ushort*)alloc((size_t)256 * K23 * sizeof(ushort));
  ushort* xb     = (ushort*)alloc((size_t)NN * CIN * sizeof(ushort));
  ushort* tmp    = (ushort*)alloc((size_t)NN * CHID * sizeof(ushort));  // bf16 pre-BN h
  float*  stats  = (float*)alloc(6 * CHID * sizeof(float));  // [layer][sum|sq][256]
  float*  pooled = (float*)alloc((size_t)NB * CHID * sizeof(float));
  float*  counts = (float*)alloc(NB * sizeof(float));
  (void)ws_size; (void)n_in; (void)in_sizes; (void)out_size;

  float* cs1 = stats + 0 * 512, *cq1 = stats + 0 * 512 + 256;
  float* cs2 = stats + 1 * 512, *cq2 = stats + 1 * 512 + 256;
  float* cs3 = stats + 2 * 512, *cq3 = stats + 2 * 512 + 256;

  // CSR + static aggregates
  k_init<<<cdiv(NN + 1, 256), 256, 0, stream>>>(ptr, pooled, counts, stats);
  k_count<<<1250 + 40, 256, 0, stream>>>(ei, ptr, batch, counts);
  k_scan<<<1, 1024, 0, stream>>>(ptr, pos, degf);
  k_fill<<<1250, 256, 0, stream>>>(ei, pos, perm, srcs);
  k_permprep<<<20000 + 1250 + 1472, 256, 0, stream>>>((const float4*)eattr, perm, eattrs,
                                                      (const float4*)x, degf, A1, xb,
                                                      W1, W2, W3, Wt1, Wt2, Wt3);
  k_eag<<<NN / 4, 256, 0, stream>>>(eattrs, xb, ptr, srcs, A1, A23);

  dim3 ggrid(cdiv(NN, 128), CHID / 64);

  // layer 1
  k_gemm<<<ggrid, 256, 0, stream>>>(A1, Wt1, b1, degf, tmp, cs1, cq1, K1);
  k_gbn<<<NN / 4, 256, 0, stream>>>(tmp, cs1, cq1, g1, be1, ptr, srcs, degf, A23);

  // layer 2
  k_gemm<<<ggrid, 256, 0, stream>>>(A23, Wt2, b2, degf, tmp, cs2, cq2, K23);
  k_gbn<<<NN / 4, 256, 0, stream>>>(tmp, cs2, cq2, g2, be2, ptr, srcs, degf, A23);

  // layer 3
  k_gemm<<<ggrid, 256, 0, stream>>>(A23, Wt3, b3, degf, tmp, cs3, cq3, K23);
  k_poolbn<<<cdiv(NN, 64), 256, 0, stream>>>(tmp, cs3, cq3, g3, be3, batch, pooled);

  // MLP head
  k_mlp<<<NB, 512, 0, stream>>>(pooled, counts, nbr, fc1w, fc1b, fc2w, fc2b, out);
}

// Round 11
// 400.279 us; speedup vs baseline: 1.1735x; 1.0225x over previous
//
#include <hip/hip_runtime.h>

#define NN 10000      // nodes
#define NE 320000     // edges (before self-loops)
#define NB 64         // graphs
#define CIN 128       // in_channels
#define CEC 64        // edge_channels
#define CHID 256      // hidden
#define CMLP 512
#define CNC 4
#define K1 (2 * CIN + CEC)    // 320
#define K23 (2 * CHID + CEC)  // 576

static __host__ int cdiv(int a, int b) { return (a + b - 1) / b; }

typedef short sfrag __attribute__((ext_vector_type(8)));   // 8 bf16 in 4 VGPRs
typedef float f4 __attribute__((ext_vector_type(4)));
typedef float f2 __attribute__((ext_vector_type(2)));

static __device__ __forceinline__ ushort f2b(float f) {
  union { float f; unsigned u; } v; v.f = f;
  unsigned r = (v.u + 0x7fffu + ((v.u >> 16) & 1u)) >> 16;
  return (ushort)r;
}
static __device__ __forceinline__ float b2f(ushort u) {
  union { unsigned u; float f; } v; v.u = ((unsigned)u) << 16;
  return v.f;
}

// ---------------- setup kernels ----------------

__global__ __launch_bounds__(256) void k_init(int* __restrict__ ptr, float* __restrict__ pooled,
                                              float* __restrict__ counts, float* __restrict__ stats) {
  int i = blockIdx.x * 256 + threadIdx.x;
  if (i <= NN) ptr[i] = 0;
  if (i < NB * CHID) pooled[i] = 0.f;
  if (i < NB) counts[i] = 0.f;
  if (i < 6 * CHID) stats[i] = 0.f;
}

// blocks [0,1250): edge-degree histogram; blocks [1250,1290): batch histogram -> counts
__global__ __launch_bounds__(256) void k_count(const int* __restrict__ ei, int* __restrict__ ptr,
                                               const int* __restrict__ batch, float* __restrict__ counts) {
  int b = blockIdx.x;
  if (b < 1250) {
    int e = b * 256 + threadIdx.x;  // 1250*256 == NE exactly
    atomicAdd(&ptr[ei[NE + e] + 1], 1);
  } else {
    __shared__ int hist[NB];
    if (threadIdx.x < NB) hist[threadIdx.x] = 0;
    __syncthreads();
    int n = (b - 1250) * 256 + threadIdx.x;
    if (n < NN) atomicAdd(&hist[batch[n]], 1);
    __syncthreads();
    if (threadIdx.x < NB && hist[threadIdx.x]) atomicAdd(&counts[threadIdx.x], (float)hist[threadIdx.x]);
  }
}

// single-block inclusive scan over ptr[0..NN] + fused pos/degf writeout
__global__ __launch_bounds__(1024) void k_scan(int* __restrict__ ptr, int* __restrict__ pos,
                                               float* __restrict__ degf) {
  __shared__ int wsum[16];
  __shared__ int chtot;
  int carry = 0;
  const int n1 = NN + 1;
  const int lane = threadIdx.x & 63;
  const int wid = threadIdx.x >> 6;
  for (int base = 0; base < n1; base += 1024) {
    int i = base + threadIdx.x;
    int v = (i < n1) ? ptr[i] : 0;
    int sc = v;
#pragma unroll
    for (int d = 1; d < 64; d <<= 1) {
      int t = __shfl_up(sc, d);
      if (lane >= d) sc += t;
    }
    if (lane == 63) wsum[wid] = sc;
    __syncthreads();
    if (wid == 0 && lane < 16) {
      int ws = wsum[lane];
      int s2 = ws;
#pragma unroll
      for (int d = 1; d < 16; d <<= 1) {
        int t = __shfl_up(s2, d);
        if (lane >= d) s2 += t;
      }
      wsum[lane] = s2 - ws;  // exclusive
      if (lane == 15) chtot = s2;
    }
    __syncthreads();
    if (i < n1) ptr[i] = sc + wsum[wid] + carry;
    carry += chtot;
    __syncthreads();
  }
  for (int i = threadIdx.x; i < NN; i += 1024) {
    int p = ptr[i], q = ptr[i + 1];
    pos[i] = p;
    degf[i] = (float)(q - p + 1);  // +1 self-loop
  }
}

// counting-sort placement: srcs in CSR order + perm (original e -> sorted slot)
__global__ __launch_bounds__(256) void k_fill(const int* __restrict__ ei, int* __restrict__ pos,
                                              int* __restrict__ perm, int* __restrict__ srcs) {
  int e = blockIdx.x * 256 + threadIdx.x;  // 1250*256 == NE
  int d = ei[NE + e];
  int idx = atomicAdd(&pos[d], 1);
  perm[e] = idx;
  srcs[idx] = ei[e];
}

// merged: [0,20000) permute edge_attr CSR-order fp32->bf16;
//         [20000,21250) A1[:,0:128]=bf16(degf*x), xb=bf16(x);
//         [21250,22722) weight transposes Wt1/Wt2/Wt3
__global__ __launch_bounds__(256) void k_permprep(const float4* __restrict__ eattr, const int* __restrict__ perm,
                                                  ushort* __restrict__ eattrs, const float4* __restrict__ x,
                                                  const float* __restrict__ degf, ushort* __restrict__ A1,
                                                  ushort* __restrict__ xb, const float* __restrict__ W1,
                                                  const float* __restrict__ W2, const float* __restrict__ W3,
                                                  ushort* __restrict__ Wt1, ushort* __restrict__ Wt2,
                                                  ushort* __restrict__ Wt3) {
  int b = blockIdx.x;
  int tid = threadIdx.x;
  if (b < 20000) {
    int e = b * 16 + (tid >> 4);
    int c0 = (tid & 15) << 2;
    float4 v = eattr[(size_t)e * 16 + (c0 >> 2)];
    int sp = perm[e];
    ushort4 o = { f2b(v.x), f2b(v.y), f2b(v.z), f2b(v.w) };
    *(ushort4*)&eattrs[(size_t)sp * CEC + c0] = o;
  } else if (b < 21250) {
    int gid = (b - 20000) * 256 + tid;  // NN*32 = 320000
    int node = gid >> 5;
    int c4 = (gid & 31) << 2;
    float d = degf[node];
    float4 v = x[gid];
    ushort4 o = { f2b(d * v.x), f2b(d * v.y), f2b(d * v.z), f2b(d * v.w) };
    *(ushort4*)&A1[(size_t)node * K1 + c4] = o;
    ushort4 xo = { f2b(v.x), f2b(v.y), f2b(v.z), f2b(v.w) };
    *(ushort4*)&xb[(size_t)node * CIN + c4] = xo;
  } else {
    int j = (b - 21250) * 256 + tid;  // 256*(K1+2*K23) = 376832
    const float* W; ushort* Wt; int Ktot;
    if (j < 256 * K1) { W = W1; Wt = Wt1; Ktot = K1; }
    else {
      j -= 256 * K1;
      if (j < 256 * K23) { W = W2; Wt = Wt2; Ktot = K23; }
      else { j -= 256 * K23; W = W3; Wt = Wt3; Ktot = K23; }
    }
    int n = j / Ktot;
    int k = j - n * Ktot;
    Wt[j] = f2b(W[(size_t)k * CHID + n]);
  }
}

// fused: ea_sum (512B wave-loads over CSR-ordered eattrs: 4 rows/load) + layer-1 x-gather
__global__ __launch_bounds__(256) void k_eag(const ushort* __restrict__ eattrs, const ushort* __restrict__ xb,
                                             const int* __restrict__ ptr, const int* __restrict__ srcs,
                                             ushort* __restrict__ A1, ushort* __restrict__ A23) {
  int node = blockIdx.x * 4 + (threadIdx.x >> 6);
  int lane = threadIdx.x & 63;
  int s = ptr[node], e = ptr[node + 1];
  int nrows = e - s;
  const int lane16 = lane & 15;
  const int lgrp = lane >> 4;

  // ea-sum: lane l holds channels 4*(l&15)..+3 of row (4g + l>>4). One 512B wave-load per 4 rows.
  float4 av = {0.f, 0.f, 0.f, 0.f};
  const ushort* ebase = eattrs + (size_t)s * CEC;
  int full4 = nrows & ~3;
#pragma unroll 2
  for (int r0 = 0; r0 < full4; r0 += 4) {
    ushort4 v = *(const ushort4*)&ebase[(size_t)(r0 + lgrp) * CEC + lane16 * 4];
    av.x += b2f(v.x); av.y += b2f(v.y); av.z += b2f(v.z); av.w += b2f(v.w);
  }
  if (full4 + lgrp < nrows) {
    ushort4 v = *(const ushort4*)&ebase[(size_t)(full4 + lgrp) * CEC + lane16 * 4];
    av.x += b2f(v.x); av.y += b2f(v.y); av.z += b2f(v.z); av.w += b2f(v.w);
  }
  av.x += __shfl_xor(av.x, 16); av.x += __shfl_xor(av.x, 32);
  av.y += __shfl_xor(av.y, 16); av.y += __shfl_xor(av.y, 32);
  av.z += __shfl_xor(av.z, 16); av.z += __shfl_xor(av.z, 32);
  av.w += __shfl_xor(av.w, 16); av.w += __shfl_xor(av.w, 32);
  if (lane < 16) {  // +1.0 self-loop fill
    ushort4 eo = { f2b(av.x + 1.f), f2b(av.y + 1.f), f2b(av.z + 1.f), f2b(av.w + 1.f) };
    *(ushort4*)&A1[(size_t)node * K1 + 2 * CIN + lane16 * 4] = eo;
    *(ushort4*)&A23[(size_t)node * K23 + 2 * CHID + lane16 * 4] = eo;
  }

  // layer-1 gather: 32-wide pipelined chunks, uniform-break tail
  ushort2 own = *(const ushort2*)&xb[(size_t)node * CIN + lane * 2];
  float gx = b2f(own.x), gy = b2f(own.y);
  int myi = (lane < 32 && s + lane < e) ? srcs[s + lane] : 0;
  for (int k0 = s; k0 < e; k0 += 32) {
    int rem = e - k0;
    int cur = myi;
    int nk = k0 + 32;
    if (nk < e) myi = (lane < 32 && nk + lane < e) ? srcs[nk + lane] : 0;
    if (rem >= 32) {
#pragma unroll
      for (int j = 0; j < 32; ++j) {
        int idx = __shfl(cur, j);
        ushort2 v = *(const ushort2*)&xb[(size_t)idx * CIN + lane * 2];
        gx += b2f(v.x); gy += b2f(v.y);
      }
    } else {
#pragma unroll
      for (int j = 0; j < 32; ++j) {
        if (j >= rem) break;  // wave-uniform: no load issued past rem
        int idx = __shfl(cur, j);
        ushort2 v = *(const ushort2*)&xb[(size_t)idx * CIN + lane * 2];
        gx += b2f(v.x); gy += b2f(v.y);
      }
    }
  }
  ushort2 go = { f2b(gx), f2b(gy) };
  *(ushort2*)&A1[(size_t)node * K1 + CIN + lane * 2] = go;
}

// layers 2/3: fused BN-apply + gather. Own row from bf16 tmp; neighbor rows from fp8 table
// (2.56 MB -> fits per-XCD 4 MB L2; halves gather bytes vs bf16).
__global__ __launch_bounds__(256) void k_gbn(const ushort* __restrict__ tmp, const unsigned* __restrict__ t8,
                                             const float* __restrict__ colsum, const float* __restrict__ colsq,
                                             const float* __restrict__ g, const float* __restrict__ be,
                                             const int* __restrict__ ptr, const int* __restrict__ srcs,
                                             const float* __restrict__ degf, ushort* __restrict__ A23) {
  int node = blockIdx.x * 4 + (threadIdx.x >> 6);
  int lane = threadIdx.x & 63;
  int c4 = lane << 2;
  float sc[4], sh[4];
#pragma unroll
  for (int j = 0; j < 4; ++j) {
    int c = c4 + j;
    float mu = colsum[c] * (1.f / (float)NN);
    float var = colsq[c] * (1.f / (float)NN) - mu * mu;
    float inv = rsqrtf(var + 1e-5f);
    sc[j] = g[c] * inv;
    sh[j] = be[c] - mu * sc[j];
  }
  // own row (bf16, full precision path: dh-panel + self term)
  ushort4 tv = *(const ushort4*)&tmp[(size_t)node * CHID + c4];
  float o0 = fmaxf(fmaf(b2f(tv.x), sc[0], sh[0]), 0.f);
  float o1 = fmaxf(fmaf(b2f(tv.y), sc[1], sh[1]), 0.f);
  float o2 = fmaxf(fmaf(b2f(tv.z), sc[2], sh[2]), 0.f);
  float o3 = fmaxf(fmaf(b2f(tv.w), sc[3], sh[3]), 0.f);
  float d = degf[node];
  ushort4 ao = { f2b(d * o0), f2b(d * o1), f2b(d * o2), f2b(d * o3) };
  *(ushort4*)&A23[(size_t)node * K23 + c4] = ao;

  // gather: G = h_node + sum over neighbors of relu(bn(fp8(tmp[src])))
  float ax = o0, ay = o1, az = o2, aw = o3;
  int s = ptr[node], e = ptr[node + 1];
  int myi = (lane < 32 && s + lane < e) ? srcs[s + lane] : 0;
  for (int k0 = s; k0 < e; k0 += 32) {
    int rem = e - k0;
    int cur = myi;
    int nk = k0 + 32;
    if (nk < e) myi = (lane < 32 && nk + lane < e) ? srcs[nk + lane] : 0;
    if (rem >= 32) {
#pragma unroll
      for (int j = 0; j < 32; ++j) {
        int idx = __shfl(cur, j);
        unsigned u = t8[(size_t)idx * 64 + lane];
        f2 lo = __builtin_amdgcn_cvt_pk_f32_fp8(u, false);
        f2 hi = __builtin_amdgcn_cvt_pk_f32_fp8(u, true);
        ax += fmaxf(fmaf(lo.x, sc[0], sh[0]), 0.f);
        ay += fmaxf(fmaf(lo.y, sc[1], sh[1]), 0.f);
        az += fmaxf(fmaf(hi.x, sc[2], sh[2]), 0.f);
        aw += fmaxf(fmaf(hi.y, sc[3], sh[3]), 0.f);
      }
    } else {
#pragma unroll
      for (int j = 0; j < 32; ++j) {
        if (j >= rem) break;  // wave-uniform: no load issued past rem
        int idx = __shfl(cur, j);
        unsigned u = t8[(size_t)idx * 64 + lane];
        f2 lo = __builtin_amdgcn_cvt_pk_f32_fp8(u, false);
        f2 hi = __builtin_amdgcn_cvt_pk_f32_fp8(u, true);
        ax += fmaxf(fmaf(lo.x, sc[0], sh[0]), 0.f);
        ay += fmaxf(fmaf(lo.y, sc[1], sh[1]), 0.f);
        az += fmaxf(fmaf(hi.x, sc[2], sh[2]), 0.f);
        aw += fmaxf(fmaf(hi.y, sc[3], sh[3]), 0.f);
      }
    }
  }
  ushort4 o = { f2b(ax), f2b(ay), f2b(az), f2b(aw) };
  *(ushort4*)&A23[(size_t)node * K23 + CHID + c4] = o;
}

// ---------------- MFMA GEMM (128x64 tile) + fused bias/relu/BN-stats; bf16 + fp8 out ----------------
__global__ __launch_bounds__(256) void k_gemm(const ushort* __restrict__ Ag, const ushort* __restrict__ Wt,
                                              const float* __restrict__ bias, const float* __restrict__ degf,
                                              ushort* __restrict__ outb, unsigned char* __restrict__ out8,
                                              float* __restrict__ colsum, float* __restrict__ colsq, int Ktot) {
  __shared__ ushort As[128 * 40];  // 128 rows x 32 k, stride 40
  __shared__ ushort Bs[64 * 40];   // 64 n x 32 k
  const int bm = blockIdx.x * 128;
  const int bn = blockIdx.y * 64;
  const int tid = threadIdx.x;
  const int w = tid >> 6;
  const int lane = tid & 63;
  const int ln = lane & 15;
  const int quad = lane >> 4;

  f4 acc[2][4];
#pragma unroll
  for (int mf = 0; mf < 2; ++mf)
#pragma unroll
    for (int nf = 0; nf < 4; ++nf) acc[mf][nf] = (f4){0.f, 0.f, 0.f, 0.f};

  const int rA = tid >> 1;
  const int hk = (tid & 1) << 4;  // 0 or 16
  const int rowA = bm + rA;
  const int nB = tid >> 2;
  const int kq = (tid & 3) << 3;  // 0,8,16,24

  for (int k0 = 0; k0 < Ktot; k0 += 32) {
    uint4 v0 = {0, 0, 0, 0}, v1 = {0, 0, 0, 0};
    if (rowA < NN) {
      const uint4* p = (const uint4*)(Ag + (size_t)rowA * Ktot + k0 + hk);
      v0 = p[0]; v1 = p[1];
    }
    *(uint4*)&As[rA * 40 + hk] = v0;
    *(uint4*)&As[rA * 40 + hk + 8] = v1;
    uint4 bv = *(const uint4*)(Wt + (size_t)(bn + nB) * Ktot + k0 + kq);
    *(uint4*)&Bs[nB * 40 + kq] = bv;
    __syncthreads();

    sfrag a0 = *(const sfrag*)&As[(w * 32 + ln) * 40 + quad * 8];
    sfrag a1 = *(const sfrag*)&As[(w * 32 + 16 + ln) * 40 + quad * 8];
#pragma unroll
    for (int nf = 0; nf < 4; ++nf) {
      sfrag b = *(const sfrag*)&Bs[(nf * 16 + ln) * 40 + quad * 8];
      acc[0][nf] = __builtin_amdgcn_mfma_f32_16x16x32_bf16(a0, b, acc[0][nf], 0, 0, 0);
      acc[1][nf] = __builtin_amdgcn_mfma_f32_16x16x32_bf16(a1, b, acc[1][nf], 0, 0, 0);
    }
    __syncthreads();
  }

  float bcol[4];
#pragma unroll
  for (int nf = 0; nf < 4; ++nf) bcol[nf] = bias[bn + nf * 16 + ln];
  float ssum[4] = {0.f, 0.f, 0.f, 0.f}, sqq[4] = {0.f, 0.f, 0.f, 0.f};
#pragma unroll
  for (int mf = 0; mf < 2; ++mf) {
    int rbase = bm + w * 32 + mf * 16 + quad * 4;
#pragma unroll
    for (int r = 0; r < 4; ++r) {
      int row = rbase + r;
      bool valid = row < NN;
      float d = valid ? degf[row] : 0.f;
#pragma unroll
      for (int nf = 0; nf < 4; ++nf) {
        float v = fmaxf(acc[mf][nf][r] + d * bcol[nf], 0.f);
        if (valid) {
          size_t oidx = (size_t)row * CHID + bn + nf * 16 + ln;
          outb[oidx] = f2b(v);
          int enc = __builtin_amdgcn_cvt_pk_fp8_f32(v, v, 0, false);
          out8[oidx] = (unsigned char)enc;
          ssum[nf] += v;
          sqq[nf] += v * v;
        }
      }
    }
  }
#pragma unroll
  for (int nf = 0; nf < 4; ++nf) {
    float s = ssum[nf], q = sqq[nf];
    s += __shfl_xor(s, 16); s += __shfl_xor(s, 32);
    q += __shfl_xor(q, 16); q += __shfl_xor(q, 32);
    if (quad == 0) {
      atomicAdd(&colsum[bn + nf * 16 + ln], s);
      atomicAdd(&colsq[bn + nf * 16 + ln], q);
    }
  }
}

// ---------------- layer-3 BN + relu + segment pool, fused (bf16 in) ----------------
__global__ __launch_bounds__(256) void k_poolbn(const ushort* __restrict__ t, const float* __restrict__ colsum,
                                                const float* __restrict__ colsq, const float* __restrict__ g,
                                                const float* __restrict__ be, const int* __restrict__ batch,
                                                float* __restrict__ pooled) {
  __shared__ int bsh[64];
  int r0 = blockIdx.x * 64;
  int c = threadIdx.x;
  int rows = min(64, NN - r0);
  if (c < rows) bsh[c] = batch[r0 + c];
  __syncthreads();
  float mu = colsum[c] * (1.f / (float)NN);
  float var = colsq[c] * (1.f / (float)NN) - mu * mu;
  float inv = rsqrtf(var + 1e-5f);
  float sc = g[c] * inv;
  float sh = be[c] - mu * sc;
  float acc = 0.f;
  int cur = bsh[0];
  for (int r = 0; r < rows; ++r) {
    int gg = bsh[r];
    if (gg != cur) {
      atomicAdd(&pooled[cur * CHID + c], acc);
      acc = 0.f;
      cur = gg;
    }
    acc += fmaxf(fmaf(b2f(t[(size_t)(r0 + r) * CHID + c]), sc, sh), 0.f);
  }
  atomicAdd(&pooled[cur * CHID + c], acc);
}

// ---------------- MLP head: one block per graph, 512 threads, shfl reduce ----------------
__global__ __launch_bounds__(512) void k_mlp(const float* __restrict__ pooled, const float* __restrict__ counts,
                                             const float* __restrict__ nb, const float* __restrict__ w1,
                                             const float* __restrict__ b1, const float* __restrict__ w2,
                                             const float* __restrict__ b2, float* __restrict__ out) {
  int g = blockIdx.x;
  int t = threadIdx.x;
  int wid = t >> 6, wl = t & 63;
  __shared__ float zin[CHID + 1 + CIN];  // 385
  __shared__ float red[8];
  if (t < CHID) zin[t] = pooled[g * CHID + t];
  else if (t == CHID) zin[CHID] = counts[g] * 0.025f;  // / MAX_SIZE(40)
  else if (t < CHID + 1 + CIN) zin[t] = nb[g * CIN + (t - CHID - 1)];
  __syncthreads();
  float acc = b1[t];
  for (int k = 0; k < CHID + 1 + CIN; ++k) acc = fmaf(zin[k], w1[k * CMLP + t], acc);
  float z = fmaxf(acc, 0.f);
#pragma unroll
  for (int n = 0; n < CNC; ++n) {
    float part = z * w2[t * CNC + n];
#pragma unroll
    for (int d = 1; d < 64; d <<= 1) part += __shfl_xor(part, d);
    if (wl == 0) red[wid] = part;
    __syncthreads();
    if (t == 0) {
      float tot = 0.f;
#pragma unroll
      for (int i = 0; i < 8; ++i) tot += red[i];
      out[g * CNC + n] = tot + b2[n];
    }
    __syncthreads();
  }
}

// ---------------- launch ----------------

extern "C" void kernel_launch(void* const* d_in, const int* in_sizes, int n_in,
                              void* d_out, int out_size, void* d_ws, size_t ws_size,
                              hipStream_t stream) {
  const float* x     = (const float*)d_in[0];
  const int*   ei    = (const int*)d_in[1];
  const float* eattr = (const float*)d_in[2];
  const int*   batch = (const int*)d_in[3];
  const float* nbr   = (const float*)d_in[4];
  const float* W1 = (const float*)d_in[5];
  const float* b1 = (const float*)d_in[6];
  const float* g1 = (const float*)d_in[7];
  const float* be1 = (const float*)d_in[8];
  const float* W2 = (const float*)d_in[9];
  const float* b2 = (const float*)d_in[10];
  const float* g2 = (const float*)d_in[11];
  const float* be2 = (const float*)d_in[12];
  const float* W3 = (const float*)d_in[13];
  const float* b3 = (const float*)d_in[14];
  const float* g3 = (const float*)d_in[15];
  const float* be3 = (const float*)d_in[16];
  const float* fc1w = (const float*)d_in[17];
  const float* fc1b = (const float*)d_in[18];
  const float* fc2w = (const float*)d_in[19];
  const float* fc2b = (const float*)d_in[20];
  float* out = (float*)d_out;

  char* ws = (char*)d_ws;
  size_t off = 0;
  auto alloc = [&](size_t bytes) {
    void* p = ws + off;
    off = (off + bytes + 255) & ~(size_t)255;
    return p;
  };
  int*    ptr    = (int*)alloc((NN + 1) * sizeof(int));
  int*    pos    = (int*)alloc(NN * sizeof(int));
  float*  degf   = (float*)alloc(NN * sizeof(float));
  int*    perm   = (int*)alloc(NE * sizeof(int));
  int*    srcs   = (int*)alloc(NE * sizeof(int));
  ushort* eattrs = (ushort*)alloc((size_t)NE * CEC * sizeof(ushort));  // 41 MB CSR-ordered bf16
  ushort* A1     = (ushort*)alloc((size_t)NN * K1 * sizeof(ushort));
  ushort* A23    = (ushort*)alloc((size_t)NN * K23 * sizeof(ushort));
  ushort* Wt1    = (ushort*)alloc((size_t)256 * K1 * sizeof(ushort));
  ushort* Wt2    = (ushort*)alloc((size_t)256 * K23 * sizeof(ushort));
  ushort* Wt3    = (ushort*)alloc((size_t)256 * K23 * sizeof(ushort));
  ushort* xb     = (ushort*)alloc((size_t)NN * CIN * sizeof(ushort));
  ushort* tmp    = (ushort*)alloc((size_t)NN * CHID * sizeof(ushort));        // bf16 pre-BN h
  unsigned char* tmp8 = (unsigned char*)alloc((size_t)NN * CHID);             // fp8 pre-BN h (L2-resident)
  float*  stats  = (float*)alloc(6 * CHID * sizeof(float));  // [layer][sum|sq][256]
  float*  pooled = (float*)alloc((size_t)NB * CHID * sizeof(float));
  float*  counts = (float*)alloc(NB * sizeof(float));
  (void)ws_size; (void)n_in; (void)in_sizes; (void)out_size;

  float* cs1 = stats + 0 * 512, *cq1 = stats + 0 * 512 + 256;
  float* cs2 = stats + 1 * 512, *cq2 = stats + 1 * 512 + 256;
  float* cs3 = stats + 2 * 512, *cq3 = stats + 2 * 512 + 256;

  // CSR + static aggregates
  k_init<<<cdiv(NN + 1, 256), 256, 0, stream>>>(ptr, pooled, counts, stats);
  k_count<<<1250 + 40, 256, 0, stream>>>(ei, ptr, batch, counts);
  k_scan<<<1, 1024, 0, stream>>>(ptr, pos, degf);
  k_fill<<<1250, 256, 0, stream>>>(ei, pos, perm, srcs);
  k_permprep<<<20000 + 1250 + 1472, 256, 0, stream>>>((const float4*)eattr, perm, eattrs,
                                                      (const float4*)x, degf, A1, xb,
                                                      W1, W2, W3, Wt1, Wt2, Wt3);
  k_eag<<<NN / 4, 256, 0, stream>>>(eattrs, xb, ptr, srcs, A1, A23);

  dim3 ggrid(cdiv(NN, 128), CHID / 64);

  // layer 1
  k_gemm<<<ggrid, 256, 0, stream>>>(A1, Wt1, b1, degf, tmp, tmp8, cs1, cq1, K1);
  k_gbn<<<NN / 4, 256, 0, stream>>>(tmp, (const unsigned*)tmp8, cs1, cq1, g1, be1, ptr, srcs, degf, A23);

  // layer 2
  k_gemm<<<ggrid, 256, 0, stream>>>(A23, Wt2, b2, degf, tmp, tmp8, cs2, cq2, K23);
  k_gbn<<<NN / 4, 256, 0, stream>>>(tmp, (const unsigned*)tmp8, cs2, cq2, g2, be2, ptr, srcs, degf, A23);

  // layer 3
  k_gemm<<<ggrid, 256, 0, stream>>>(A23, Wt3, b3, degf, tmp, tmp8, cs3, cq3, K23);
  k_poolbn<<<cdiv(NN, 64), 256, 0, stream>>>(tmp, cs3, cq3, g3, be3, batch, pooled);

  // MLP head
  k_mlp<<<NB, 512, 0, stream>>>(pooled, counts, nbr, fc1w, fc1b, fc2w, fc2b, out);
}

// Round 12
// 382.773 us; speedup vs baseline: 1.2272x; 1.0457x over previous
//
#include <hip/hip_runtime.h>

#define NN 10000      // nodes
#define NE 320000     // edges (before self-loops)
#define NB 64         // graphs
#define CIN 128       // in_channels
#define CEC 64        // edge_channels
#define CHID 256      // hidden
#define CMLP 512
#define CNC 4
#define K1 (2 * CIN + CEC)    // 320
#define K23 (2 * CHID + CEC)  // 576

static __host__ int cdiv(int a, int b) { return (a + b - 1) / b; }

typedef short sfrag __attribute__((ext_vector_type(8)));   // 8 bf16 in 4 VGPRs
typedef float f4 __attribute__((ext_vector_type(4)));
typedef float f2 __attribute__((ext_vector_type(2)));

static __device__ __forceinline__ ushort f2b(float f) {
  union { float f; unsigned u; } v; v.f = f;
  unsigned r = (v.u + 0x7fffu + ((v.u >> 16) & 1u)) >> 16;
  return (ushort)r;
}
static __device__ __forceinline__ float b2f(ushort u) {
  union { unsigned u; float f; } v; v.u = ((unsigned)u) << 16;
  return v.f;
}

// ---------------- setup kernels ----------------

__global__ __launch_bounds__(256) void k_init(int* __restrict__ ptr, float* __restrict__ pooled,
                                              float* __restrict__ counts, float* __restrict__ stats) {
  int i = blockIdx.x * 256 + threadIdx.x;
  if (i <= NN) ptr[i] = 0;
  if (i < NB * CHID) pooled[i] = 0.f;
  if (i < NB) counts[i] = 0.f;
  if (i < 6 * CHID) stats[i] = 0.f;
}

// blocks [0,1250): edge-degree histogram; blocks [1250,1290): batch histogram -> counts
__global__ __launch_bounds__(256) void k_count(const int* __restrict__ ei, int* __restrict__ ptr,
                                               const int* __restrict__ batch, float* __restrict__ counts) {
  int b = blockIdx.x;
  if (b < 1250) {
    int e = b * 256 + threadIdx.x;  // 1250*256 == NE exactly
    atomicAdd(&ptr[ei[NE + e] + 1], 1);
  } else {
    __shared__ int hist[NB];
    if (threadIdx.x < NB) hist[threadIdx.x] = 0;
    __syncthreads();
    int n = (b - 1250) * 256 + threadIdx.x;
    if (n < NN) atomicAdd(&hist[batch[n]], 1);
    __syncthreads();
    if (threadIdx.x < NB && hist[threadIdx.x]) atomicAdd(&counts[threadIdx.x], (float)hist[threadIdx.x]);
  }
}

// ---------------- parallel 3-phase scan over ptr[0..NN] ----------------
// A: 40 blocks, local inclusive scan of 256-chunks into scn, chunk totals into csum
__global__ __launch_bounds__(256) void k_scanA(const int* __restrict__ ptr, int* __restrict__ scn,
                                               int* __restrict__ csum) {
  int b = blockIdx.x, t = threadIdx.x;
  int i = b * 256 + t;
  int lane = t & 63, wid = t >> 6;
  __shared__ int ws[4];
  int v = (i <= NN) ? ptr[i] : 0;
  int sc = v;
#pragma unroll
  for (int d = 1; d < 64; d <<= 1) {
    int tt = __shfl_up(sc, d);
    if (lane >= d) sc += tt;
  }
  if (lane == 63) ws[wid] = sc;
  __syncthreads();
  int add = 0;
#pragma unroll
  for (int w = 0; w < 3; ++w) if (w < wid) add += ws[w];
  sc += add;
  if (i <= NN) scn[i] = sc;
  if (t == 255) csum[b] = sc;
}

// B: exclusive scan of 40 chunk totals
__global__ __launch_bounds__(64) void k_scanB(const int* __restrict__ csum, int* __restrict__ coff) {
  int l = threadIdx.x;
  int v = (l < 40) ? csum[l] : 0;
  int sc = v;
#pragma unroll
  for (int d = 1; d < 64; d <<= 1) {
    int tt = __shfl_up(sc, d);
    if (l >= d) sc += tt;
  }
  if (l < 40) coff[l] = sc - v;
}

// C: finalize ptr + pos + degf (reads scn only -> race-free)
__global__ __launch_bounds__(256) void k_scanC(const int* __restrict__ scn, const int* __restrict__ coff,
                                               int* __restrict__ ptr, int* __restrict__ pos,
                                               float* __restrict__ degf) {
  int b = blockIdx.x, t = threadIdx.x;
  int i = b * 256 + t;
  if (i > NN) return;
  int cb = coff[b];
  int fin = scn[i] + cb;
  ptr[i] = fin;
  if (i < NN) {
    int nxt = (t == 255) ? scn[i + 1] + coff[b + 1] : scn[i + 1] + cb;
    pos[i] = fin;
    degf[i] = (float)(nxt - fin + 1);  // +1 self-loop
  }
}

// counting-sort placement: srcs in CSR order + perm (original e -> sorted slot)
__global__ __launch_bounds__(256) void k_fill(const int* __restrict__ ei, int* __restrict__ pos,
                                              int* __restrict__ perm, int* __restrict__ srcs) {
  int e = blockIdx.x * 256 + threadIdx.x;  // 1250*256 == NE
  int d = ei[NE + e];
  int idx = atomicAdd(&pos[d], 1);
  perm[e] = idx;
  srcs[idx] = ei[e];
}

// merged: [0,20000) permute edge_attr CSR-order fp32->fp8;
//         [20000,21250) A1[:,0:128]=bf16(degf*x), xb=bf16(x);
//         [21250,22722) weight transposes Wt1/Wt2/Wt3
__global__ __launch_bounds__(256) void k_permprep(const float4* __restrict__ eattr, const int* __restrict__ perm,
                                                  unsigned char* __restrict__ eattrs8, const float4* __restrict__ x,
                                                  const float* __restrict__ degf, ushort* __restrict__ A1,
                                                  ushort* __restrict__ xb, const float* __restrict__ W1,
                                                  const float* __restrict__ W2, const float* __restrict__ W3,
                                                  ushort* __restrict__ Wt1, ushort* __restrict__ Wt2,
                                                  ushort* __restrict__ Wt3) {
  int b = blockIdx.x;
  int tid = threadIdx.x;
  if (b < 20000) {
    int e = b * 16 + (tid >> 4);
    int c0 = (tid & 15) << 2;
    float4 v = eattr[(size_t)e * 16 + (c0 >> 2)];
    int sp = perm[e];
    int w = __builtin_amdgcn_cvt_pk_fp8_f32(v.x, v.y, 0, false);
    w = __builtin_amdgcn_cvt_pk_fp8_f32(v.z, v.w, w, true);
    *(unsigned*)&eattrs8[(size_t)sp * CEC + c0] = (unsigned)w;
  } else if (b < 21250) {
    int gid = (b - 20000) * 256 + tid;  // NN*32 = 320000
    int node = gid >> 5;
    int c4 = (gid & 31) << 2;
    float d = degf[node];
    float4 v = x[gid];
    ushort4 o = { f2b(d * v.x), f2b(d * v.y), f2b(d * v.z), f2b(d * v.w) };
    *(ushort4*)&A1[(size_t)node * K1 + c4] = o;
    ushort4 xo = { f2b(v.x), f2b(v.y), f2b(v.z), f2b(v.w) };
    *(ushort4*)&xb[(size_t)node * CIN + c4] = xo;
  } else {
    int j = (b - 21250) * 256 + tid;  // 256*(K1+2*K23) = 376832
    const float* W; ushort* Wt; int Ktot;
    if (j < 256 * K1) { W = W1; Wt = Wt1; Ktot = K1; }
    else {
      j -= 256 * K1;
      if (j < 256 * K23) { W = W2; Wt = Wt2; Ktot = K23; }
      else { j -= 256 * K23; W = W3; Wt = Wt3; Ktot = K23; }
    }
    int n = j / Ktot;
    int k = j - n * Ktot;
    Wt[j] = f2b(W[(size_t)k * CHID + n]);
  }
}

// fused: ea_sum (fp8 rows, 512B wave-loads: 8 rows/load) + layer-1 x-gather
__global__ __launch_bounds__(256) void k_eag(const unsigned char* __restrict__ eattrs8,
                                             const ushort* __restrict__ xb,
                                             const int* __restrict__ ptr, const int* __restrict__ srcs,
                                             ushort* __restrict__ A1, ushort* __restrict__ A23) {
  int node = blockIdx.x * 4 + (threadIdx.x >> 6);
  int lane = threadIdx.x & 63;
  int s = ptr[node], e = ptr[node + 1];
  int nrows = e - s;

  // ea-sum: lane l holds channels 8*(l&7)..+7 of row (8g + l>>3). uint2/lane = 8 rows per wave-load.
  const int lrow = lane >> 3;   // 0..7
  const int lch = lane & 7;     // channel-group
  float a0 = 0.f, a1 = 0.f, a2 = 0.f, a3 = 0.f, a4 = 0.f, a5 = 0.f, a6 = 0.f, a7 = 0.f;
  const uint2* e8 = (const uint2*)(eattrs8 + (size_t)s * CEC);
  int full8 = nrows & ~7;
  for (int r0 = 0; r0 < full8; r0 += 8) {
    uint2 u = e8[(size_t)(r0 + lrow) * 8 + lch];
    f2 p0 = __builtin_amdgcn_cvt_pk_f32_fp8(u.x, false);
    f2 p1 = __builtin_amdgcn_cvt_pk_f32_fp8(u.x, true);
    f2 p2 = __builtin_amdgcn_cvt_pk_f32_fp8(u.y, false);
    f2 p3 = __builtin_amdgcn_cvt_pk_f32_fp8(u.y, true);
    a0 += p0.x; a1 += p0.y; a2 += p1.x; a3 += p1.y;
    a4 += p2.x; a5 += p2.y; a6 += p3.x; a7 += p3.y;
  }
  if (full8 + lrow < nrows) {  // tail (reads stay inside padded alloc)
    uint2 u = e8[(size_t)(full8 + lrow) * 8 + lch];
    f2 p0 = __builtin_amdgcn_cvt_pk_f32_fp8(u.x, false);
    f2 p1 = __builtin_amdgcn_cvt_pk_f32_fp8(u.x, true);
    f2 p2 = __builtin_amdgcn_cvt_pk_f32_fp8(u.y, false);
    f2 p3 = __builtin_amdgcn_cvt_pk_f32_fp8(u.y, true);
    a0 += p0.x; a1 += p0.y; a2 += p1.x; a3 += p1.y;
    a4 += p2.x; a5 += p2.y; a6 += p3.x; a7 += p3.y;
  }
#pragma unroll
  for (int m = 8; m < 64; m <<= 1) {
    a0 += __shfl_xor(a0, m); a1 += __shfl_xor(a1, m);
    a2 += __shfl_xor(a2, m); a3 += __shfl_xor(a3, m);
    a4 += __shfl_xor(a4, m); a5 += __shfl_xor(a5, m);
    a6 += __shfl_xor(a6, m); a7 += __shfl_xor(a7, m);
  }
  if (lane < 8) {  // +1.0 self-loop fill; lane writes channels 8*lane..+7
    ushort o[8] = { f2b(a0 + 1.f), f2b(a1 + 1.f), f2b(a2 + 1.f), f2b(a3 + 1.f),
                    f2b(a4 + 1.f), f2b(a5 + 1.f), f2b(a6 + 1.f), f2b(a7 + 1.f) };
    uint4 pk = *(const uint4*)o;
    *(uint4*)&A1[(size_t)node * K1 + 2 * CIN + lane * 8] = pk;
    *(uint4*)&A23[(size_t)node * K23 + 2 * CHID + lane * 8] = pk;
  }

  // layer-1 gather: 32-wide pipelined chunks, uniform-break tail
  ushort2 own = *(const ushort2*)&xb[(size_t)node * CIN + lane * 2];
  float gx = b2f(own.x), gy = b2f(own.y);
  int myi = (lane < 32 && s + lane < e) ? srcs[s + lane] : 0;
  for (int k0 = s; k0 < e; k0 += 32) {
    int rem = e - k0;
    int cur = myi;
    int nk = k0 + 32;
    if (nk < e) myi = (lane < 32 && nk + lane < e) ? srcs[nk + lane] : 0;
    if (rem >= 32) {
#pragma unroll
      for (int j = 0; j < 32; ++j) {
        int idx = __shfl(cur, j);
        ushort2 v = *(const ushort2*)&xb[(size_t)idx * CIN + lane * 2];
        gx += b2f(v.x); gy += b2f(v.y);
      }
    } else {
#pragma unroll
      for (int j = 0; j < 32; ++j) {
        if (j >= rem) break;  // wave-uniform: no load issued past rem
        int idx = __shfl(cur, j);
        ushort2 v = *(const ushort2*)&xb[(size_t)idx * CIN + lane * 2];
        gx += b2f(v.x); gy += b2f(v.y);
      }
    }
  }
  ushort2 go = { f2b(gx), f2b(gy) };
  *(ushort2*)&A1[(size_t)node * K1 + CIN + lane * 2] = go;
}

// layers 2/3: fused BN-apply + gather. Own row from bf16 tmp; neighbor rows from fp8 table.
__global__ __launch_bounds__(256) void k_gbn(const ushort* __restrict__ tmp, const unsigned* __restrict__ t8,
                                             const float* __restrict__ colsum, const float* __restrict__ colsq,
                                             const float* __restrict__ g, const float* __restrict__ be,
                                             const int* __restrict__ ptr, const int* __restrict__ srcs,
                                             const float* __restrict__ degf, ushort* __restrict__ A23) {
  int node = blockIdx.x * 4 + (threadIdx.x >> 6);
  int lane = threadIdx.x & 63;
  int c4 = lane << 2;
  float sc[4], sh[4];
#pragma unroll
  for (int j = 0; j < 4; ++j) {
    int c = c4 + j;
    float mu = colsum[c] * (1.f / (float)NN);
    float var = colsq[c] * (1.f / (float)NN) - mu * mu;
    float inv = rsqrtf(var + 1e-5f);
    sc[j] = g[c] * inv;
    sh[j] = be[c] - mu * sc[j];
  }
  // own row (bf16, full precision path: dh-panel + self term)
  ushort4 tv = *(const ushort4*)&tmp[(size_t)node * CHID + c4];
  float o0 = fmaxf(fmaf(b2f(tv.x), sc[0], sh[0]), 0.f);
  float o1 = fmaxf(fmaf(b2f(tv.y), sc[1], sh[1]), 0.f);
  float o2 = fmaxf(fmaf(b2f(tv.z), sc[2], sh[2]), 0.f);
  float o3 = fmaxf(fmaf(b2f(tv.w), sc[3], sh[3]), 0.f);
  float d = degf[node];
  ushort4 ao = { f2b(d * o0), f2b(d * o1), f2b(d * o2), f2b(d * o3) };
  *(ushort4*)&A23[(size_t)node * K23 + c4] = ao;

  // gather: G = h_node + sum over neighbors of relu(bn(fp8(tmp[src])))
  float ax = o0, ay = o1, az = o2, aw = o3;
  int s = ptr[node], e = ptr[node + 1];
  int myi = (lane < 32 && s + lane < e) ? srcs[s + lane] : 0;
  for (int k0 = s; k0 < e; k0 += 32) {
    int rem = e - k0;
    int cur = myi;
    int nk = k0 + 32;
    if (nk < e) myi = (lane < 32 && nk + lane < e) ? srcs[nk + lane] : 0;
    if (rem >= 32) {
#pragma unroll
      for (int j = 0; j < 32; ++j) {
        int idx = __shfl(cur, j);
        unsigned u = t8[(size_t)idx * 64 + lane];
        f2 lo = __builtin_amdgcn_cvt_pk_f32_fp8(u, false);
        f2 hi = __builtin_amdgcn_cvt_pk_f32_fp8(u, true);
        ax += fmaxf(fmaf(lo.x, sc[0], sh[0]), 0.f);
        ay += fmaxf(fmaf(lo.y, sc[1], sh[1]), 0.f);
        az += fmaxf(fmaf(hi.x, sc[2], sh[2]), 0.f);
        aw += fmaxf(fmaf(hi.y, sc[3], sh[3]), 0.f);
      }
    } else {
#pragma unroll
      for (int j = 0; j < 32; ++j) {
        if (j >= rem) break;  // wave-uniform: no load issued past rem
        int idx = __shfl(cur, j);
        unsigned u = t8[(size_t)idx * 64 + lane];
        f2 lo = __builtin_amdgcn_cvt_pk_f32_fp8(u, false);
        f2 hi = __builtin_amdgcn_cvt_pk_f32_fp8(u, true);
        ax += fmaxf(fmaf(lo.x, sc[0], sh[0]), 0.f);
        ay += fmaxf(fmaf(lo.y, sc[1], sh[1]), 0.f);
        az += fmaxf(fmaf(hi.x, sc[2], sh[2]), 0.f);
        aw += fmaxf(fmaf(hi.y, sc[3], sh[3]), 0.f);
      }
    }
  }
  ushort4 o = { f2b(ax), f2b(ay), f2b(az), f2b(aw) };
  *(ushort4*)&A23[(size_t)node * K23 + CHID + c4] = o;
}

// ---------------- MFMA GEMM (128x64 tile, register-prefetch dbuf) + fused bias/relu/BN-stats ----------------
__global__ __launch_bounds__(256) void k_gemm(const ushort* __restrict__ Ag, const ushort* __restrict__ Wt,
                                              const float* __restrict__ bias, const float* __restrict__ degf,
                                              ushort* __restrict__ outb, unsigned char* __restrict__ out8,
                                              float* __restrict__ colsum, float* __restrict__ colsq, int Ktot) {
  __shared__ ushort As[128 * 40];  // 128 rows x 32 k, stride 40
  __shared__ ushort Bs[64 * 40];   // 64 n x 32 k
  const int bm = blockIdx.x * 128;
  const int bn = blockIdx.y * 64;
  const int tid = threadIdx.x;
  const int w = tid >> 6;
  const int lane = tid & 63;
  const int ln = lane & 15;
  const int quad = lane >> 4;

  f4 acc[2][4];
#pragma unroll
  for (int mf = 0; mf < 2; ++mf)
#pragma unroll
    for (int nf = 0; nf < 4; ++nf) acc[mf][nf] = (f4){0.f, 0.f, 0.f, 0.f};

  const int rA = tid >> 1;
  const int hk = (tid & 1) << 4;  // 0 or 16
  const int rowA = bm + rA;
  const int nB = tid >> 2;
  const int kq = (tid & 3) << 3;  // 0,8,16,24
  // clamped row pointer: rows >= NN compute garbage accs that are never stored
  const ushort* ap = Ag + (size_t)min(rowA, NN - 1) * Ktot + hk;
  const ushort* bp = Wt + (size_t)(bn + nB) * Ktot + kq;

  const int iters = Ktot >> 5;
  uint4 av0 = ((const uint4*)ap)[0];
  uint4 av1 = ((const uint4*)ap)[1];
  uint4 bv = *(const uint4*)bp;
  for (int it = 0; it < iters; ++it) {
    *(uint4*)&As[rA * 40 + hk] = av0;
    *(uint4*)&As[rA * 40 + hk + 8] = av1;
    *(uint4*)&Bs[nB * 40 + kq] = bv;
    __syncthreads();
    if (it + 1 < iters) {  // prefetch next K-tile while MFMAs consume LDS
      const ushort* apn = ap + (it + 1) * 32;
      av0 = ((const uint4*)apn)[0];
      av1 = ((const uint4*)apn)[1];
      bv = *(const uint4*)(bp + (it + 1) * 32);
    }
    sfrag a0 = *(const sfrag*)&As[(w * 32 + ln) * 40 + quad * 8];
    sfrag a1 = *(const sfrag*)&As[(w * 32 + 16 + ln) * 40 + quad * 8];
#pragma unroll
    for (int nf = 0; nf < 4; ++nf) {
      sfrag b = *(const sfrag*)&Bs[(nf * 16 + ln) * 40 + quad * 8];
      acc[0][nf] = __builtin_amdgcn_mfma_f32_16x16x32_bf16(a0, b, acc[0][nf], 0, 0, 0);
      acc[1][nf] = __builtin_amdgcn_mfma_f32_16x16x32_bf16(a1, b, acc[1][nf], 0, 0, 0);
    }
    __syncthreads();
  }

  float bcol[4];
#pragma unroll
  for (int nf = 0; nf < 4; ++nf) bcol[nf] = bias[bn + nf * 16 + ln];
  float ssum[4] = {0.f, 0.f, 0.f, 0.f}, sqq[4] = {0.f, 0.f, 0.f, 0.f};
#pragma unroll
  for (int mf = 0; mf < 2; ++mf) {
    int rbase = bm + w * 32 + mf * 16 + quad * 4;
#pragma unroll
    for (int r = 0; r < 4; ++r) {
      int row = rbase + r;
      bool valid = row < NN;
      float d = valid ? degf[row] : 0.f;
#pragma unroll
      for (int nf = 0; nf < 4; ++nf) {
        float v = fmaxf(acc[mf][nf][r] + d * bcol[nf], 0.f);
        if (valid) {
          size_t oidx = (size_t)row * CHID + bn + nf * 16 + ln;
          outb[oidx] = f2b(v);
          int enc = __builtin_amdgcn_cvt_pk_fp8_f32(v, v, 0, false);
          out8[oidx] = (unsigned char)enc;
          ssum[nf] += v;
          sqq[nf] += v * v;
        }
      }
    }
  }
#pragma unroll
  for (int nf = 0; nf < 4; ++nf) {
    float s = ssum[nf], q = sqq[nf];
    s += __shfl_xor(s, 16); s += __shfl_xor(s, 32);
    q += __shfl_xor(q, 16); q += __shfl_xor(q, 32);
    if (quad == 0) {
      atomicAdd(&colsum[bn + nf * 16 + ln], s);
      atomicAdd(&colsq[bn + nf * 16 + ln], q);
    }
  }
}

// ---------------- layer-3 BN + relu + segment pool, fused (bf16 in) ----------------
__global__ __launch_bounds__(256) void k_poolbn(const ushort* __restrict__ t, const float* __restrict__ colsum,
                                                const float* __restrict__ colsq, const float* __restrict__ g,
                                                const float* __restrict__ be, const int* __restrict__ batch,
                                                float* __restrict__ pooled) {
  __shared__ int bsh[64];
  int r0 = blockIdx.x * 64;
  int c = threadIdx.x;
  int rows = min(64, NN - r0);
  if (c < rows) bsh[c] = batch[r0 + c];
  __syncthreads();
  float mu = colsum[c] * (1.f / (float)NN);
  float var = colsq[c] * (1.f / (float)NN) - mu * mu;
  float inv = rsqrtf(var + 1e-5f);
  float sc = g[c] * inv;
  float sh = be[c] - mu * sc;
  float acc = 0.f;
  int cur = bsh[0];
  for (int r = 0; r < rows; ++r) {
    int gg = bsh[r];
    if (gg != cur) {
      atomicAdd(&pooled[cur * CHID + c], acc);
      acc = 0.f;
      cur = gg;
    }
    acc += fmaxf(fmaf(b2f(t[(size_t)(r0 + r) * CHID + c]), sc, sh), 0.f);
  }
  atomicAdd(&pooled[cur * CHID + c], acc);
}

// ---------------- MLP head: one block per graph, 512 threads, shfl reduce ----------------
__global__ __launch_bounds__(512) void k_mlp(const float* __restrict__ pooled, const float* __restrict__ counts,
                                             const float* __restrict__ nb, const float* __restrict__ w1,
                                             const float* __restrict__ b1, const float* __restrict__ w2,
                                             const float* __restrict__ b2, float* __restrict__ out) {
  int g = blockIdx.x;
  int t = threadIdx.x;
  int wid = t >> 6, wl = t & 63;
  __shared__ float zin[CHID + 1 + CIN];  // 385
  __shared__ float red[8];
  if (t < CHID) zin[t] = pooled[g * CHID + t];
  else if (t == CHID) zin[CHID] = counts[g] * 0.025f;  // / MAX_SIZE(40)
  else if (t < CHID + 1 + CIN) zin[t] = nb[g * CIN + (t - CHID - 1)];
  __syncthreads();
  float acc = b1[t];
  for (int k = 0; k < CHID + 1 + CIN; ++k) acc = fmaf(zin[k], w1[k * CMLP + t], acc);
  float z = fmaxf(acc, 0.f);
#pragma unroll
  for (int n = 0; n < CNC; ++n) {
    float part = z * w2[t * CNC + n];
#pragma unroll
    for (int d = 1; d < 64; d <<= 1) part += __shfl_xor(part, d);
    if (wl == 0) red[wid] = part;
    __syncthreads();
    if (t == 0) {
      float tot = 0.f;
#pragma unroll
      for (int i = 0; i < 8; ++i) tot += red[i];
      out[g * CNC + n] = tot + b2[n];
    }
    __syncthreads();
  }
}

// ---------------- launch ----------------

extern "C" void kernel_launch(void* const* d_in, const int* in_sizes, int n_in,
                              void* d_out, int out_size, void* d_ws, size_t ws_size,
                              hipStream_t stream) {
  const float* x     = (const float*)d_in[0];
  const int*   ei    = (const int*)d_in[1];
  const float* eattr = (const float*)d_in[2];
  const int*   batch = (const int*)d_in[3];
  const float* nbr   = (const float*)d_in[4];
  const float* W1 = (const float*)d_in[5];
  const float* b1 = (const float*)d_in[6];
  const float* g1 = (const float*)d_in[7];
  const float* be1 = (const float*)d_in[8];
  const float* W2 = (const float*)d_in[9];
  const float* b2 = (const float*)d_in[10];
  const float* g2 = (const float*)d_in[11];
  const float* be2 = (const float*)d_in[12];
  const float* W3 = (const float*)d_in[13];
  const float* b3 = (const float*)d_in[14];
  const float* g3 = (const float*)d_in[15];
  const float* be3 = (const float*)d_in[16];
  const float* fc1w = (const float*)d_in[17];
  const float* fc1b = (const float*)d_in[18];
  const float* fc2w = (const float*)d_in[19];
  const float* fc2b = (const float*)d_in[20];
  float* out = (float*)d_out;

  char* ws = (char*)d_ws;
  size_t off = 0;
  auto alloc = [&](size_t bytes) {
    void* p = ws + off;
    off = (off + bytes + 255) & ~(size_t)255;
    return p;
  };
  int*    ptr    = (int*)alloc((NN + 1) * sizeof(int));
  int*    pos    = (int*)alloc(NN * sizeof(int));
  int*    scn    = (int*)alloc((NN + 1) * sizeof(int));
  int*    csum   = (int*)alloc(64 * sizeof(int));
  int*    coff   = (int*)alloc(64 * sizeof(int));
  float*  degf   = (float*)alloc(NN * sizeof(float));
  int*    perm   = (int*)alloc(NE * sizeof(int));
  int*    srcs   = (int*)alloc(NE * sizeof(int));
  unsigned char* eattrs8 = (unsigned char*)alloc((size_t)(NE + 8) * CEC);  // 20.5 MB fp8 CSR-ordered
  ushort* A1     = (ushort*)alloc((size_t)NN * K1 * sizeof(ushort));
  ushort* A23    = (ushort*)alloc((size_t)NN * K23 * sizeof(ushort));
  ushort* Wt1    = (ushort*)alloc((size_t)256 * K1 * sizeof(ushort));
  ushort* Wt2    = (ushort*)alloc((size_t)256 * K23 * sizeof(ushort));
  ushort* Wt3    = (ushort*)alloc((size_t)256 * K23 * sizeof(ushort));
  ushort* xb     = (ushort*)alloc((size_t)NN * CIN * sizeof(ushort));
  ushort* tmp    = (ushort*)alloc((size_t)NN * CHID * sizeof(ushort));        // bf16 pre-BN h
  unsigned char* tmp8 = (unsigned char*)alloc((size_t)NN * CHID);             // fp8 pre-BN h (L2-resident)
  float*  stats  = (float*)alloc(6 * CHID * sizeof(float));  // [layer][sum|sq][256]
  float*  pooled = (float*)alloc((size_t)NB * CHID * sizeof(float));
  float*  counts = (float*)alloc(NB * sizeof(float));
  (void)ws_size; (void)n_in; (void)in_sizes; (void)out_size;

  float* cs1 = stats + 0 * 512, *cq1 = stats + 0 * 512 + 256;
  float* cs2 = stats + 1 * 512, *cq2 = stats + 1 * 512 + 256;
  float* cs3 = stats + 2 * 512, *cq3 = stats + 2 * 512 + 256;

  // CSR + static aggregates
  k_init<<<cdiv(NN + 1, 256), 256, 0, stream>>>(ptr, pooled, counts, stats);
  k_count<<<1250 + 40, 256, 0, stream>>>(ei, ptr, batch, counts);
  k_scanA<<<40, 256, 0, stream>>>(ptr, scn, csum);
  k_scanB<<<1, 64, 0, stream>>>(csum, coff);
  k_scanC<<<40, 256, 0, stream>>>(scn, coff, ptr, pos, degf);
  k_fill<<<1250, 256, 0, stream>>>(ei, pos, perm, srcs);
  k_permprep<<<20000 + 1250 + 1472, 256, 0, stream>>>((const float4*)eattr, perm, eattrs8,
                                                      (const float4*)x, degf, A1, xb,
                                                      W1, W2, W3, Wt1, Wt2, Wt3);
  k_eag<<<NN / 4, 256, 0, stream>>>(eattrs8, xb, ptr, srcs, A1, A23);

  dim3 ggrid(cdiv(NN, 128), CHID / 64);

  // layer 1
  k_gemm<<<ggrid, 256, 0, stream>>>(A1, Wt1, b1, degf, tmp, tmp8, cs1, cq1, K1);
  k_gbn<<<NN / 4, 256, 0, stream>>>(tmp, (const unsigned*)tmp8, cs1, cq1, g1, be1, ptr, srcs, degf, A23);

  // layer 2
  k_gemm<<<ggrid, 256, 0, stream>>>(A23, Wt2, b2, degf, tmp, tmp8, cs2, cq2, K23);
  k_gbn<<<NN / 4, 256, 0, stream>>>(tmp, (const unsigned*)tmp8, cs2, cq2, g2, be2, ptr, srcs, degf, A23);

  // layer 3
  k_gemm<<<ggrid, 256, 0, stream>>>(A23, Wt3, b3, degf, tmp, tmp8, cs3, cq3, K23);
  k_poolbn<<<cdiv(NN, 64), 256, 0, stream>>>(tmp, cs3, cq3, g3, be3, batch, pooled);

  // MLP head
  k_mlp<<<NB, 512, 0, stream>>>(pooled, counts, nbr, fc1w, fc1b, fc2w, fc2b, out);
}